// Round 2
// baseline (44776.871 us; speedup 1.0000x reference)
//
#include <hip/hip_runtime.h>

#define WIDTH 1024
#define NHH 16
#define HDD 64
#define MBSZ 16
#define BBB 4
#define LLL 2048
#define NCHUNK 128

typedef __attribute__((ext_vector_type(4))) float f32x4;
typedef __attribute__((ext_vector_type(8))) short short8;

__device__ __forceinline__ short f2bf(float f) {
  unsigned u = __float_as_uint(f);
  u = (u + 0x7FFFu + ((u >> 16) & 1u)) >> 16;  // RNE f32->bf16
  return (short)u;
}
__device__ __forceinline__ float gelu_f(float x) {
  float x2 = x * x;
  float t = tanhf(0.79788456f * x * (1.0f + 0.044715f * x2));
  return 0.5f * x * (1.0f + t);
}
__device__ __forceinline__ float gelu_bwd_f(float x) {
  float x2 = x * x;
  float t = tanhf(0.79788456f * x * (1.0f + 0.044715f * x2));
  return 0.5f * x * ((1.0f - t * t) * (0.79788456f + 0.1070322243f * x2)) + 0.5f * (1.0f + t);
}
__device__ __forceinline__ float dot4(f32x4 a, f32x4 b) {
  return a[0] * b[0] + a[1] * b[1] + a[2] * b[2] + a[3] * b[3];
}

// ---------------- C[M=8192][1024] = A[8192][1024] @ W[1024][1024]^T (bf16 MFMA, fp32 in/out)
__global__ __launch_bounds__(256) void gemm_bt(const float* __restrict__ A,
                                               const float* __restrict__ W,
                                               float* __restrict__ C) {
  __shared__ __align__(16) short sA[64][40];
  __shared__ __align__(16) short sB[64][40];
  const int tid = threadIdx.x;
  const int m0 = blockIdx.x * 64, n0 = blockIdx.y * 64;
  const int srow = tid >> 2, sk = (tid & 3) * 8;
  const int wv = tid >> 6, ln = tid & 63;
  const int fr = ln & 15, kh = (ln >> 4) * 8;
  f32x4 acc[4];
#pragma unroll
  for (int s = 0; s < 4; ++s) acc[s] = (f32x4){0.f, 0.f, 0.f, 0.f};
  const float* ga = A + (long)(m0 + srow) * 1024 + sk;
  const float* gw = W + (long)(n0 + srow) * 1024 + sk;
  for (int k0 = 0; k0 < 1024; k0 += 32) {
    f32x4 a0 = *(const f32x4*)(ga + k0);
    f32x4 a1 = *(const f32x4*)(ga + k0 + 4);
    f32x4 w0 = *(const f32x4*)(gw + k0);
    f32x4 w1 = *(const f32x4*)(gw + k0 + 4);
    short8 pa, pw;
    pa[0] = f2bf(a0[0]); pa[1] = f2bf(a0[1]); pa[2] = f2bf(a0[2]); pa[3] = f2bf(a0[3]);
    pa[4] = f2bf(a1[0]); pa[5] = f2bf(a1[1]); pa[6] = f2bf(a1[2]); pa[7] = f2bf(a1[3]);
    pw[0] = f2bf(w0[0]); pw[1] = f2bf(w0[1]); pw[2] = f2bf(w0[2]); pw[3] = f2bf(w0[3]);
    pw[4] = f2bf(w1[0]); pw[5] = f2bf(w1[1]); pw[6] = f2bf(w1[2]); pw[7] = f2bf(w1[3]);
    *(short8*)&sA[srow][sk] = pa;
    *(short8*)&sB[srow][sk] = pw;
    __syncthreads();
    short8 af = *(const short8*)&sA[wv * 16 + fr][kh];
#pragma unroll
    for (int s = 0; s < 4; ++s) {
      short8 bf8 = *(const short8*)&sB[s * 16 + fr][kh];
      acc[s] = __builtin_amdgcn_mfma_f32_16x16x32_bf16(af, bf8, acc[s], 0, 0, 0);
    }
    __syncthreads();
  }
  const int orow = m0 + wv * 16 + (ln >> 4) * 4;
#pragma unroll
  for (int s = 0; s < 4; ++s)
#pragma unroll
    for (int q = 0; q < 4; ++q)
      C[(long)(orow + q) * 1024 + n0 + s * 16 + fr] = acc[s][q];
}

// ---------------- lr_eta[b,h,t] = sigmoid(hs[t]·lr_w[h] + lr_b[h]) / 64
__global__ __launch_bounds__(256) void lr_kernel(const float* __restrict__ hs,
                                                 const float* __restrict__ lrw,
                                                 const float* __restrict__ lrb,
                                                 float* __restrict__ out) {
  __shared__ __align__(16) float row[1024];
  const int t = blockIdx.x, tid = threadIdx.x;
  *(f32x4*)&row[tid * 4] = *(const f32x4*)&hs[(long)t * 1024 + tid * 4];
  __syncthreads();
  const int hh = tid >> 4, j = tid & 15;
  const float* wrow = lrw + hh * 1024;
  float s = 0.f;
#pragma unroll 4
  for (int m = 0; m < 16; ++m) {
    const int c = j * 4 + m * 64;
    s += dot4(*(const f32x4*)&row[c], *(const f32x4*)&wrow[c]);
  }
#pragma unroll
  for (int o = 8; o; o >>= 1) s += __shfl_xor(s, o, 16);
  if (j == 0) {
    const float v = s + lrb[hh];
    const float sg = 1.f / (1.f + expf(-v));
    const int b = t >> 11, tr = t & 2047;
    out[((b << 4) + hh) * 2048 + tr] = sg * (1.f / 64.f);
  }
}

// ---------------- sequential TTT scan: one block of 1024 per (b,h)
__global__ __launch_bounds__(1024, 4) void scan_kernel(
    float* __restrict__ Qb, const float* __restrict__ Kb, const float* __restrict__ Vb,
    const float* __restrict__ LRb, const float* __restrict__ lti,
    const float* __restrict__ nw, const float* __restrict__ nb,
    const float* __restrict__ W1in, const float* __restrict__ b1in,
    const float* __restrict__ W2in, const float* __restrict__ b2in,
    float* __restrict__ W2S) {
  __shared__ __align__(16) float sW1c[256 * 64];   // W1 state, col-major + XOR swizzle
  __shared__ __align__(16) float sX2[16][257];
  __shared__ __align__(16) float sXb[16][257];
  __shared__ __align__(16) float sG1[16][257];
  __shared__ __align__(16) float sX1[16][68];
  __shared__ __align__(16) float sXQ[16][68];
  __shared__ __align__(16) float sTg[16][68];
  __shared__ __align__(16) float sZ2[16][68];
  __shared__ __align__(16) float sG2[16][68];
  __shared__ __align__(16) float sC[16][17];
  __shared__ __align__(16) float sB1[256];
  __shared__ __align__(16) float sB2[64];
  __shared__ float sLr[16];
  __shared__ float sTok[16];
  __shared__ __align__(16) float sLnw[64];
  __shared__ __align__(16) float sLnb[64];

  const int bh = blockIdx.x;
  const int b = bh >> 4, h = bh & 15;
  const int tid = threadIdx.x;
  const int p = tid & 255;       // column owner (256 hidden dim)
  const int q = tid >> 8;        // row quarter (4 rows each)
  const int r0 = q * 4;
  const int wv = tid >> 6;       // wave 0..15 (== row i for 16x64 outputs)
  const int ln = tid & 63;       // lane (== d for 16x64 outputs)

  for (int e = tid; e < 64 * 256; e += 1024) {
    int pd = e & 255, dd = e >> 8;
    sW1c[pd * 64 + (((dd >> 2) ^ (pd & 7)) << 2) + (dd & 3)] = W1in[h * 16384 + e];
  }
  if (tid < 256) sB1[tid] = b1in[h * 256 + tid];
  if (tid < 64) { sB2[tid] = b2in[h * 64 + tid]; sLnw[tid] = nw[h * 64 + tid]; sLnb[tid] = nb[h * 64 + tid]; }
  if (tid < 16) sTok[tid] = fmaxf(1.0f / (float)(tid + 1) + lti[tid], 0.0f);
  __syncthreads();

  float* __restrict__ W2s = W2S + (long)bh * 16384;

  for (int n = 0; n < NCHUNK; ++n) {
    const long gbase = ((long)(b * LLL + n * MBSZ)) * WIDTH + h * HDD;
    const float* __restrict__ w2p = (n == 0) ? (W2in + h * 16384) : W2s;

    // ---- phase 0: load chunk (one element per thread, coalesced)
    {
      const long a = gbase + (long)wv * WIDTH + ln;
      const float kv = Kb[a];
      sX1[wv][ln] = kv;
      sXQ[wv][ln] = Qb[a];
      sTg[wv][ln] = Vb[a] - kv;
    }
    if (tid < 16) sLr[tid] = LRb[(long)bh * 2048 + n * MBSZ + tid];
    __syncthreads();  // A

    // ---- phase 1: z1/q1 (4 rows per thread, col p) + X2; C1 via wave shuffles
    float z1[4], q1[4];
    {
      const float bp = sB1[p];
#pragma unroll
      for (int r = 0; r < 4; ++r) { z1[r] = bp; q1[r] = 0.f; }
#pragma unroll
      for (int dq = 0; dq < 16; ++dq) {
        const f32x4 w = *(const f32x4*)&sW1c[p * 64 + ((dq ^ (p & 7)) << 2)];
#pragma unroll
        for (int r = 0; r < 4; ++r) {
          z1[r] += dot4(*(const f32x4*)&sX1[r0 + r][dq * 4], w);
          q1[r] += dot4(*(const f32x4*)&sXQ[r0 + r][dq * 4], w);
        }
      }
#pragma unroll
      for (int r = 0; r < 4; ++r) sX2[r0 + r][p] = gelu_f(z1[r]);
    }
    {  // C1[i][j] = (i>=j) ? tok[i]*lr[j]*(XQ_i·X1_j + 1) : 0
      const int cj = ln & 15, qq = ln >> 4;
      float s = 0.f;
#pragma unroll
      for (int dd = 0; dd < 4; ++dd) {
        const int dq = qq * 4 + dd;
        s += dot4(*(const f32x4*)&sXQ[wv][dq * 4], *(const f32x4*)&sX1[cj][dq * 4]);
      }
      s += __shfl_xor(s, 16, 64);
      s += __shfl_xor(s, 32, 64);
      if (qq == 0) sC[wv][cj] = (wv >= cj) ? sTok[wv] * sLr[cj] * (s + 1.0f) : 0.0f;
    }
    __syncthreads();  // B

    // ---- phase 2: Z2 = X2@W2 + b2 (one output per thread)
    {
      const float* __restrict__ wc = w2p + ln;
      float za = 0.f;
#pragma unroll 16
      for (int pp = 0; pp < 256; ++pp) za += sX2[wv][pp] * wc[pp * 64];
      sZ2[wv][ln] = za + sB2[ln];
    }
    __syncthreads();  // C

    // ---- phase 3: gZ2 = ln_l2_bwd(Z2, V-K)  (tid<256)
    if (tid < 256) {
      const int i = tid >> 4, j = tid & 15;
      const f32x4 z = *(const f32x4*)&sZ2[i][j * 4];
      float s1 = z[0] + z[1] + z[2] + z[3];
      float s2 = z[0] * z[0] + z[1] * z[1] + z[2] * z[2] + z[3] * z[3];
#pragma unroll
      for (int o = 8; o; o >>= 1) { s1 += __shfl_xor(s1, o, 16); s2 += __shfl_xor(s2, o, 16); }
      const float mu = s1 * (1.f / 64.f);
      const float rstd = rsqrtf(s2 * (1.f / 64.f) - mu * mu + 1e-6f);
      const f32x4 g = *(const f32x4*)&sLnw[j * 4];
      const f32x4 bb = *(const f32x4*)&sLnb[j * 4];
      const f32x4 tg = *(const f32x4*)&sTg[i][j * 4];
      f32x4 xh, gx;
      float a1 = 0.f, a2 = 0.f;
#pragma unroll
      for (int e = 0; e < 4; ++e) {
        xh[e] = (z[e] - mu) * rstd;
        gx[e] = (g[e] * xh[e] + bb[e] - tg[e]) * g[e];
        a1 += gx[e]; a2 += gx[e] * xh[e];
      }
#pragma unroll
      for (int o = 8; o; o >>= 1) { a1 += __shfl_xor(a1, o, 16); a2 += __shfl_xor(a2, o, 16); }
      const float m1 = a1 * (1.f / 64.f), m2 = a2 * (1.f / 64.f);
      f32x4 o4;
#pragma unroll
      for (int e = 0; e < 4; ++e) o4[e] = (gx[e] - m1 - xh[e] * m2) * rstd;
      *(f32x4*)&sG2[i][j * 4] = o4;
    }
    __syncthreads();  // D

    // ---- phase 4: gZ1 = (gZ2 @ W2^T) * gelu_bwd(Z1) -> sG1
    {
      const float* __restrict__ wrow = w2p + p * 64;
      float acc[4] = {0.f, 0.f, 0.f, 0.f};
#pragma unroll
      for (int dq = 0; dq < 16; ++dq) {
        const f32x4 w = *(const f32x4*)&wrow[dq * 4];
#pragma unroll
        for (int r = 0; r < 4; ++r)
          acc[r] += dot4(*(const f32x4*)&sG2[r0 + r][dq * 4], w);
      }
#pragma unroll
      for (int r = 0; r < 4; ++r) sG1[r0 + r][p] = acc[r] * gelu_bwd_f(z1[r]);
    }
    __syncthreads();  // E1

    // ---- phase 5: X2_bar = gelu(XQ@W1 + b1 - C1@gZ1)
    {
#pragma unroll
      for (int r = 0; r < 4; ++r) {
        const int i = r0 + r;
        float v = q1[r] + sB1[p];
        for (int j = 0; j <= i; ++j) v -= sC[i][j] * sG1[j][p];
        sXb[i][p] = gelu_f(v);
      }
    }
    __syncthreads();  // E

    // ---- phase 6: C2 via shuffles; za = X2_bar@W2 (regs)
    float za;
    {
      const int cj = ln & 15, qq = ln >> 4;
      float s = 0.f;
#pragma unroll 8
      for (int t = 0; t < 64; ++t) {
        const int pp = qq * 64 + t;
        s += sXb[wv][pp] * sX2[cj][pp];
      }
      s += __shfl_xor(s, 16, 64);
      s += __shfl_xor(s, 32, 64);
      if (qq == 0) sC[wv][cj] = (wv >= cj) ? sTok[wv] * sLr[cj] * (s + 1.0f) : 0.0f;
    }
    {
      const float* __restrict__ wc = w2p + ln;
      za = 0.f;
#pragma unroll 16
      for (int pp = 0; pp < 256; ++pp) za += sXb[wv][pp] * wc[pp * 64];
    }
    __syncthreads();  // F

    // ---- phase 7: Z2_bar = za + b2 - C2@gZ2
    {
      float corr = 0.f;
#pragma unroll
      for (int j = 0; j < 16; ++j) corr += sC[wv][j] * sG2[j][ln];
      sZ2[wv][ln] = za + sB2[ln] - corr;
    }
    __syncthreads();  // G

    // ---- phase 8: XQW out (tid<256) + state updates (all threads)
    if (tid < 256) {
      const int i = tid >> 4, j = tid & 15;
      const f32x4 z = *(const f32x4*)&sZ2[i][j * 4];
      float s1 = z[0] + z[1] + z[2] + z[3];
      float s2 = z[0] * z[0] + z[1] * z[1] + z[2] * z[2] + z[3] * z[3];
#pragma unroll
      for (int o = 8; o; o >>= 1) { s1 += __shfl_xor(s1, o, 16); s2 += __shfl_xor(s2, o, 16); }
      const float mu = s1 * (1.f / 64.f);
      const float rstd = rsqrtf(s2 * (1.f / 64.f) - mu * mu + 1e-6f);
      const f32x4 g = *(const f32x4*)&sLnw[j * 4];
      const f32x4 bb = *(const f32x4*)&sLnb[j * 4];
      const f32x4 xq = *(const f32x4*)&sXQ[i][j * 4];
      f32x4 o4;
#pragma unroll
      for (int e = 0; e < 4; ++e) o4[e] = xq[e] + g[e] * ((z[e] - mu) * rstd) + bb[e];
      *(f32x4*)&Qb[gbase + (long)i * WIDTH + j * 4] = o4;
    }
    {
      const float tok15 = sTok[15];
      float nj[16], mj[16];
#pragma unroll
      for (int j = 0; j < 16; ++j) {
        const float lj = tok15 * sLr[j];
        nj[j] = lj * sG1[j][p];
        mj[j] = lj * sX2[j][p];
      }
      // W1 state (this thread's dq quarter of column p)
#pragma unroll
      for (int dd = 0; dd < 4; ++dd) {
        const int dq = q * 4 + dd;
        f32x4 a = {0.f, 0.f, 0.f, 0.f};
#pragma unroll
        for (int j = 0; j < 16; ++j) {
          const f32x4 x = *(const f32x4*)&sX1[j][dq * 4];
          a[0] += nj[j] * x[0]; a[1] += nj[j] * x[1]; a[2] += nj[j] * x[2]; a[3] += nj[j] * x[3];
        }
        f32x4* wp = (f32x4*)&sW1c[p * 64 + ((dq ^ (p & 7)) << 2)];
        f32x4 wcur = *wp;
        wcur[0] -= a[0]; wcur[1] -= a[1]; wcur[2] -= a[2]; wcur[3] -= a[3];
        *wp = wcur;
      }
      if (q == 0) {
        float s = 0.f;
#pragma unroll
        for (int j = 0; j < 16; ++j) s += nj[j];
        sB1[p] -= s;
      }
      // W2 state (row p, this thread's 16-col quarter)
#pragma unroll
      for (int dd = 0; dd < 4; ++dd) {
        const int c4 = q * 4 + dd;
        f32x4 w = *(const f32x4*)&w2p[p * 64 + c4 * 4];
#pragma unroll
        for (int j = 0; j < 16; ++j) {
          const f32x4 g = *(const f32x4*)&sG2[j][c4 * 4];
          w[0] -= mj[j] * g[0]; w[1] -= mj[j] * g[1]; w[2] -= mj[j] * g[2]; w[3] -= mj[j] * g[3];
        }
        *(f32x4*)&W2s[p * 64 + c4 * 4] = w;
      }
      if (tid < 64) {
        float s = 0.f;
#pragma unroll
        for (int j = 0; j < 16; ++j) s += tok15 * sLr[j] * sG2[j][tid];
        sB2[tid] -= s;
      }
    }
    __threadfence_block();
    __syncthreads();  // H
  }
}

// ---------------- epilogue: tmp = gelu(G) * ln_fwd(XQW, post_w, post_b)
__global__ __launch_bounds__(256) void epi_kernel(const float* __restrict__ X,
                                                  const float* __restrict__ G,
                                                  const float* __restrict__ pw,
                                                  const float* __restrict__ pb,
                                                  float* __restrict__ T) {
  __shared__ float red[8];
  const int t = blockIdx.x, tid = threadIdx.x;
  const long base = (long)t * 1024 + tid * 4;
  f32x4 x = *(const f32x4*)&X[base];
  float s1 = x[0] + x[1] + x[2] + x[3];
  float s2 = x[0] * x[0] + x[1] * x[1] + x[2] * x[2] + x[3] * x[3];
#pragma unroll
  for (int o = 32; o; o >>= 1) { s1 += __shfl_xor(s1, o, 64); s2 += __shfl_xor(s2, o, 64); }
  const int wv = tid >> 6, ln = tid & 63;
  if (ln == 0) { red[wv] = s1; red[4 + wv] = s2; }
  __syncthreads();
  s1 = red[0] + red[1] + red[2] + red[3];
  s2 = red[4] + red[5] + red[6] + red[7];
  const float mu = s1 * (1.f / 1024.f);
  const float rstd = rsqrtf(s2 * (1.f / 1024.f) - mu * mu + 1e-6f);
  f32x4 g = *(const f32x4*)&G[base];
  f32x4 w = *(const f32x4*)&pw[tid * 4];
  f32x4 bb = *(const f32x4*)&pb[tid * 4];
  f32x4 o4;
#pragma unroll
  for (int e = 0; e < 4; ++e) {
    float y = w[e] * ((x[e] - mu) * rstd) + bb[e];
    o4[e] = gelu_f(g[e]) * y;
  }
  *(f32x4*)&T[base] = o4;
}

extern "C" void kernel_launch(void* const* d_in, const int* in_sizes, int n_in,
                              void* d_out, int out_size, void* d_ws, size_t ws_size,
                              hipStream_t stream) {
  const float* hs  = (const float*)d_in[0];
  const float* Wq  = (const float*)d_in[1];
  const float* Wk  = (const float*)d_in[2];
  const float* Wv  = (const float*)d_in[3];
  const float* Wo  = (const float*)d_in[4];
  const float* Wg  = (const float*)d_in[5];
  const float* lrw = (const float*)d_in[6];
  const float* lrb = (const float*)d_in[7];
  const float* lti = (const float*)d_in[8];
  const float* nw  = (const float*)d_in[9];
  const float* nb  = (const float*)d_in[10];
  const float* W1  = (const float*)d_in[11];
  const float* b1  = (const float*)d_in[12];
  const float* W2  = (const float*)d_in[13];
  const float* b2  = (const float*)d_in[14];
  const float* pw  = (const float*)d_in[15];
  const float* pb  = (const float*)d_in[16];
  float* out = (float*)d_out;
  float* ws = (float*)d_ws;

  float* Qb  = ws;
  float* Kb  = ws + 8388608;
  float* Vb  = ws + 16777216;
  float* Gb  = ws + 25165824;
  float* LRb = ws + 33554432;
  float* W2S = ws + 33554432 + 131072;

  dim3 gg(128, 16);
  gemm_bt<<<gg, 256, 0, stream>>>(hs, Wq, Qb);
  gemm_bt<<<gg, 256, 0, stream>>>(hs, Wk, Kb);
  gemm_bt<<<gg, 256, 0, stream>>>(hs, Wv, Vb);
  gemm_bt<<<gg, 256, 0, stream>>>(hs, Wg, Gb);
  lr_kernel<<<8192, 256, 0, stream>>>(hs, lrw, lrb, LRb);
  scan_kernel<<<64, 1024, 0, stream>>>(Qb, Kb, Vb, LRb, lti, nw, nb, W1, b1, W2, b2, W2S);
  epi_kernel<<<8192, 256, 0, stream>>>(Qb, Gb, pw, pb, Kb);
  gemm_bt<<<gg, 256, 0, stream>>>(Kb, Wo, out);
}

// Round 3
// 3310.051 us; speedup vs baseline: 13.5275x; 13.5275x over previous
//
#include <hip/hip_runtime.h>

#define WIDTH 1024
#define NHH 16
#define HDD 64
#define MBSZ 16
#define BBB 4
#define LLL 2048
#define NCHUNK 128

typedef __attribute__((ext_vector_type(4))) float f32x4;
typedef __attribute__((ext_vector_type(8))) short short8;

#define MFMA16(a, b, c) __builtin_amdgcn_mfma_f32_16x16x32_bf16((a), (b), (c), 0, 0, 0)

__device__ __forceinline__ short f2bf(float f) {
  unsigned u = __float_as_uint(f);
  u = (u + 0x7FFFu + ((u >> 16) & 1u)) >> 16;  // RNE f32->bf16
  return (short)u;
}
__device__ __forceinline__ float bf2f(short s) {
  return __uint_as_float(((unsigned)(unsigned short)s) << 16);
}
__device__ __forceinline__ float gelu_f(float x) {
  float x2 = x * x;
  float t = tanhf(0.79788456f * x * (1.0f + 0.044715f * x2));
  return 0.5f * x * (1.0f + t);
}
__device__ __forceinline__ float gelu_bwd_f(float x) {
  float x2 = x * x;
  float t = tanhf(0.79788456f * x * (1.0f + 0.044715f * x2));
  return 0.5f * x * ((1.0f - t * t) * (0.79788456f + 0.1070322243f * x2)) + 0.5f * (1.0f + t);
}

// ---------------- C[8192][1024] = A[8192][1024] @ W[1024][1024]^T (bf16 MFMA, fp32 in/out)
__global__ __launch_bounds__(256) void gemm_bt(const float* __restrict__ A,
                                               const float* __restrict__ W,
                                               float* __restrict__ C) {
  __shared__ __align__(16) short sA[64][40];
  __shared__ __align__(16) short sB[64][40];
  const int tid = threadIdx.x;
  const int m0 = blockIdx.x * 64, n0 = blockIdx.y * 64;
  const int srow = tid >> 2, sk = (tid & 3) * 8;
  const int wv = tid >> 6, ln = tid & 63;
  const int fr = ln & 15, kh = (ln >> 4) * 8;
  f32x4 acc[4];
#pragma unroll
  for (int s = 0; s < 4; ++s) acc[s] = (f32x4){0.f, 0.f, 0.f, 0.f};
  const float* ga = A + (long)(m0 + srow) * 1024 + sk;
  const float* gw = W + (long)(n0 + srow) * 1024 + sk;
  for (int k0 = 0; k0 < 1024; k0 += 32) {
    f32x4 a0 = *(const f32x4*)(ga + k0);
    f32x4 a1 = *(const f32x4*)(ga + k0 + 4);
    f32x4 w0 = *(const f32x4*)(gw + k0);
    f32x4 w1 = *(const f32x4*)(gw + k0 + 4);
    short8 pa, pw;
    pa[0] = f2bf(a0[0]); pa[1] = f2bf(a0[1]); pa[2] = f2bf(a0[2]); pa[3] = f2bf(a0[3]);
    pa[4] = f2bf(a1[0]); pa[5] = f2bf(a1[1]); pa[6] = f2bf(a1[2]); pa[7] = f2bf(a1[3]);
    pw[0] = f2bf(w0[0]); pw[1] = f2bf(w0[1]); pw[2] = f2bf(w0[2]); pw[3] = f2bf(w0[3]);
    pw[4] = f2bf(w1[0]); pw[5] = f2bf(w1[1]); pw[6] = f2bf(w1[2]); pw[7] = f2bf(w1[3]);
    *(short8*)&sA[srow][sk] = pa;
    *(short8*)&sB[srow][sk] = pw;
    __syncthreads();
    short8 af = *(const short8*)&sA[wv * 16 + fr][kh];
#pragma unroll
    for (int s = 0; s < 4; ++s) {
      short8 bf8 = *(const short8*)&sB[s * 16 + fr][kh];
      acc[s] = MFMA16(af, bf8, acc[s]);
    }
    __syncthreads();
  }
  const int orow = m0 + wv * 16 + (ln >> 4) * 4;
#pragma unroll
  for (int s = 0; s < 4; ++s)
#pragma unroll
    for (int q = 0; q < 4; ++q)
      C[(long)(orow + q) * 1024 + n0 + s * 16 + fr] = acc[s][q];
}

// ---------------- lr_eta[b,h,t] = sigmoid(hs[t]·lr_w[h] + lr_b[h]) / 64
__global__ __launch_bounds__(256) void lr_kernel(const float* __restrict__ hs,
                                                 const float* __restrict__ lrw,
                                                 const float* __restrict__ lrb,
                                                 float* __restrict__ out) {
  __shared__ __align__(16) float row[1024];
  const int t = blockIdx.x, tid = threadIdx.x;
  *(f32x4*)&row[tid * 4] = *(const f32x4*)&hs[(long)t * 1024 + tid * 4];
  __syncthreads();
  const int hh = tid >> 4, j = tid & 15;
  const float* wrow = lrw + hh * 1024;
  float s = 0.f;
#pragma unroll 4
  for (int m = 0; m < 16; ++m) {
    const int c = j * 4 + m * 64;
    f32x4 x = *(const f32x4*)&row[c];
    f32x4 w = *(const f32x4*)&wrow[c];
    s += x[0] * w[0] + x[1] * w[1] + x[2] * w[2] + x[3] * w[3];
  }
#pragma unroll
  for (int o = 8; o; o >>= 1) s += __shfl_xor(s, o, 16);
  if (j == 0) {
    const float v = s + lrb[hh];
    const float sg = 1.f / (1.f + expf(-v));
    const int b = t >> 11, tr = t & 2047;
    out[((b << 4) + hh) * 2048 + tr] = sg * (1.f / 64.f);
  }
}

// ---------------- sequential TTT scan, MFMA version: one block of 512 per (b,h)
__global__ __launch_bounds__(512, 2) void scan_kernel(
    float* __restrict__ Qb, const float* __restrict__ Kb, const float* __restrict__ Vb,
    const float* __restrict__ LRb, const float* __restrict__ lti,
    const float* __restrict__ nw, const float* __restrict__ nb,
    const float* __restrict__ W1in, const float* __restrict__ b1in,
    const float* __restrict__ W2in, const float* __restrict__ b2in,
    float* __restrict__ W2S) {
  // W1 master fp32, col-major + XOR swizzle: W1[d][p] at [p*64 + ((d>>2)^(p&7))*4 + (d&3)]
  __shared__ __align__(16) float sW1c[16384];
  __shared__ __align__(16) short sW2b[256 * 72];   // bf16 W2[p][d], restaged per chunk
  __shared__ __align__(16) short sX1b[16 * 72];    // bf16 X1[i][d]
  __shared__ __align__(16) short sXQb[16 * 72];    // bf16 XQ[i][d]
  __shared__ __align__(16) float sTg[16 * 68];     // f32 (V-K)[i][d]
  __shared__ __align__(16) short sX2b[16 * 264];   // bf16 X2[i][p]
  __shared__ __align__(16) short sXbb[16 * 264];   // bf16 X2_bar[i][p]
  __shared__ __align__(16) short sG1c[256 * 24];   // bf16 gZ1 col-major [p][j]
  __shared__ __align__(16) short sG2b[16 * 72];    // bf16 gZ2[i][d]
  __shared__ __align__(16) short sG2c[64 * 24];    // bf16 gZ2 col-major [d][j]
  __shared__ __align__(16) float sZ2f[16 * 68];    // f32 Z2 / Z2_bar
  __shared__ __align__(16) short sC1b[16 * 24];    // bf16 C1'[i][j]
  __shared__ __align__(16) short sC2b[16 * 24];    // bf16 C2'[i][j]
  __shared__ __align__(16) float sB1[256];
  __shared__ __align__(16) float sB2[64];
  __shared__ float sLr[16];
  __shared__ float sTok[16];
  __shared__ __align__(16) float sLnw[64];
  __shared__ __align__(16) float sLnb[64];

  const int bh = blockIdx.x, b = bh >> 4, h = bh & 15;
  const int tid = threadIdx.x;
  const int w = tid >> 6, ln = tid & 63;
  const int fr = ln & 15, half = ln >> 4, hk = half * 8;
  const int nt0 = 2 * w;

  float* __restrict__ W2s = W2S + (long)bh * 16384;

  // preamble
  for (int e = tid; e < 16384; e += 512) {
    int dd = e >> 8, pd = e & 255;
    sW1c[pd * 64 + (((dd >> 2) ^ (pd & 7)) << 2) + (dd & 3)] = W1in[h * 16384 + e];
    W2s[e] = W2in[h * 16384 + e];
  }
  if (tid < 256) sB1[tid] = b1in[h * 256 + tid];
  if (tid < 64) { sB2[tid] = b2in[h * 64 + tid]; sLnw[tid] = nw[h * 64 + tid]; sLnb[tid] = nb[h * 64 + tid]; }
  if (tid < 16) sTok[tid] = fmaxf(1.0f / (float)(tid + 1) + lti[tid], 0.0f);
  __threadfence_block();
  __syncthreads();

  const f32x4 zf4 = (f32x4){0.f, 0.f, 0.f, 0.f};
  short8 zs8;
#pragma unroll
  for (int j = 0; j < 8; ++j) zs8[j] = 0;

  for (int n = 0; n < NCHUNK; ++n) {
    const long gbase = ((long)(b * LLL + n * MBSZ)) * WIDTH + h * HDD;

    // ---- ph0: load chunk + restage W2 bf16
    for (int e = tid; e < 1024; e += 512) {
      int i = e >> 6, d = e & 63;
      float kv = Kb[gbase + (long)i * WIDTH + d];
      float qv = Qb[gbase + (long)i * WIDTH + d];
      float vv = Vb[gbase + (long)i * WIDTH + d];
      sX1b[i * 72 + d] = f2bf(kv);
      sXQb[i * 72 + d] = f2bf(qv);
      sTg[i * 68 + d] = vv - kv;
    }
    {
      const float2* w2v = (const float2*)W2s;
      for (int e = tid; e < 8192; e += 512) {
        float2 wv = w2v[e];
        int p = e >> 5, d0 = (e & 31) * 2;
        unsigned u = ((unsigned)(unsigned short)f2bf(wv.x)) |
                     (((unsigned)(unsigned short)f2bf(wv.y)) << 16);
        *(unsigned*)&sW2b[p * 72 + d0] = u;
      }
    }
    if (tid < 16) sLr[tid] = LRb[(long)bh * 2048 + n * MBSZ + tid];
    __syncthreads();  // A

    // ---- ph1: Z1 & XQ@W1 (MFMA, wave tiles nt0,nt0+1) -> z1/q1 frags; X2->LDS; C1 (wave 0)
    short8 aX1[2], aXQ[2];
    aX1[0] = *(const short8*)&sX1b[fr * 72 + hk];
    aX1[1] = *(const short8*)&sX1b[fr * 72 + 32 + hk];
    aXQ[0] = *(const short8*)&sXQb[fr * 72 + hk];
    aXQ[1] = *(const short8*)&sXQb[fr * 72 + 32 + hk];
    f32x4 z1[2], q1[2];
#pragma unroll
    for (int t = 0; t < 2; ++t) {
      const int p = (nt0 + t) * 16 + fr;
      z1[t] = zf4; q1[t] = zf4;
#pragma unroll
      for (int ks = 0; ks < 2; ++ks) {
        const int g0 = (ks * 32 + hk) >> 2;
        f32x4 w0 = *(const f32x4*)&sW1c[p * 64 + ((g0 ^ (p & 7)) << 2)];
        f32x4 w1 = *(const f32x4*)&sW1c[p * 64 + (((g0 + 1) ^ (p & 7)) << 2)];
        short8 bw;
        bw[0] = f2bf(w0[0]); bw[1] = f2bf(w0[1]); bw[2] = f2bf(w0[2]); bw[3] = f2bf(w0[3]);
        bw[4] = f2bf(w1[0]); bw[5] = f2bf(w1[1]); bw[6] = f2bf(w1[2]); bw[7] = f2bf(w1[3]);
        z1[t] = MFMA16(aX1[ks], bw, z1[t]);
        q1[t] = MFMA16(aXQ[ks], bw, q1[t]);
      }
      const float b1p = sB1[p];
#pragma unroll
      for (int qq = 0; qq < 4; ++qq) {
        z1[t][qq] += b1p;
        sX2b[(half * 4 + qq) * 264 + p] = f2bf(gelu_f(z1[t][qq]));
      }
    }
    if (w == 0) {
      f32x4 c = zf4;
      c = MFMA16(aXQ[0], aX1[0], c);
      c = MFMA16(aXQ[1], aX1[1], c);
#pragma unroll
      for (int qq = 0; qq < 4; ++qq) {
        const int i = half * 4 + qq, j = fr;
        const float v = (i >= j) ? sTok[i] * sLr[j] * (c[qq] + 1.0f) : 0.0f;
        sC1b[i * 24 + j] = f2bf(v);
      }
    }
    __syncthreads();  // B

    // ---- ph2: Z2 = X2@W2 + b2 (waves 0-3, tile w)
    if (w < 4) {
      const int d = w * 16 + fr;
      f32x4 z2 = zf4;
#pragma unroll
      for (int ks = 0; ks < 8; ++ks) {
        short8 a = *(const short8*)&sX2b[fr * 264 + ks * 32 + hk];
        short8 bfr;
#pragma unroll
        for (int j = 0; j < 8; ++j) bfr[j] = sW2b[(ks * 32 + hk + j) * 72 + d];
        z2 = MFMA16(a, bfr, z2);
      }
      const float bb2 = sB2[d];
#pragma unroll
      for (int qq = 0; qq < 4; ++qq) sZ2f[(half * 4 + qq) * 68 + d] = z2[qq] + bb2;
    }
    __syncthreads();  // C

    // ---- ph3: gZ2 = ln_l2_bwd(Z2, V-K) (tid<256)
    if (tid < 256) {
      const int i = tid >> 4, j4 = tid & 15;
      const f32x4 z = *(const f32x4*)&sZ2f[i * 68 + j4 * 4];
      float s1 = z[0] + z[1] + z[2] + z[3];
      float s2 = z[0] * z[0] + z[1] * z[1] + z[2] * z[2] + z[3] * z[3];
#pragma unroll
      for (int o = 8; o; o >>= 1) { s1 += __shfl_xor(s1, o, 16); s2 += __shfl_xor(s2, o, 16); }
      const float mu = s1 * (1.f / 64.f);
      const float rstd = rsqrtf(s2 * (1.f / 64.f) - mu * mu + 1e-6f);
      const f32x4 g = *(const f32x4*)&sLnw[j4 * 4];
      const f32x4 bb = *(const f32x4*)&sLnb[j4 * 4];
      const f32x4 tg = *(const f32x4*)&sTg[i * 68 + j4 * 4];
      f32x4 xh, gx;
      float a1 = 0.f, a2 = 0.f;
#pragma unroll
      for (int e = 0; e < 4; ++e) {
        xh[e] = (z[e] - mu) * rstd;
        gx[e] = (g[e] * xh[e] + bb[e] - tg[e]) * g[e];
        a1 += gx[e]; a2 += gx[e] * xh[e];
      }
#pragma unroll
      for (int o = 8; o; o >>= 1) { a1 += __shfl_xor(a1, o, 16); a2 += __shfl_xor(a2, o, 16); }
      const float m1 = a1 * (1.f / 64.f), m2 = a2 * (1.f / 64.f);
#pragma unroll
      for (int e = 0; e < 4; ++e) {
        const int d = j4 * 4 + e;
        const short v = f2bf((gx[e] - m1 - xh[e] * m2) * rstd);
        sG2b[i * 72 + d] = v;
        sG2c[d * 24 + i] = v;
      }
    }
    __syncthreads();  // D

    // ---- ph4: gZ1 = (gZ2@W2^T) * gelu_bwd(Z1) -> sG1c (all waves, tiles nt0,nt0+1)
    {
      short8 aG2[2];
      aG2[0] = *(const short8*)&sG2b[fr * 72 + hk];
      aG2[1] = *(const short8*)&sG2b[fr * 72 + 32 + hk];
#pragma unroll
      for (int t = 0; t < 2; ++t) {
        const int p = (nt0 + t) * 16 + fr;
        f32x4 g = zf4;
#pragma unroll
        for (int ks = 0; ks < 2; ++ks) {
          short8 bw = *(const short8*)&sW2b[p * 72 + ks * 32 + hk];
          g = MFMA16(aG2[ks], bw, g);
        }
#pragma unroll
        for (int qq = 0; qq < 4; ++qq)
          sG1c[p * 24 + half * 4 + qq] = f2bf(g[qq] * gelu_bwd_f(z1[t][qq]));
      }
    }
    __syncthreads();  // E

    // ---- ph5: X2_bar = gelu(q1 + b1 - C1@gZ1)
    {
      short8 ac = zs8;
      if (half < 2) ac = *(const short8*)&sC1b[fr * 24 + hk];
#pragma unroll
      for (int t = 0; t < 2; ++t) {
        const int p = (nt0 + t) * 16 + fr;
        short8 bg = zs8;
        if (half < 2) bg = *(const short8*)&sG1c[p * 24 + hk];
        f32x4 corr = MFMA16(ac, bg, zf4);
        const float b1p = sB1[p];
#pragma unroll
        for (int qq = 0; qq < 4; ++qq)
          sXbb[(half * 4 + qq) * 264 + p] = f2bf(gelu_f(q1[t][qq] + b1p - corr[qq]));
      }
    }
    __syncthreads();  // F

    // ---- ph6: Z2bar partial (waves 0-3) | C2 (wave 4) | W1 update (all) | b1 update (tid>=256)
    f32x4 zbar = zf4;
    if (w < 4) {
      const int d = w * 16 + fr;
#pragma unroll
      for (int ks = 0; ks < 8; ++ks) {
        short8 a = *(const short8*)&sXbb[fr * 264 + ks * 32 + hk];
        short8 bfr;
#pragma unroll
        for (int j = 0; j < 8; ++j) bfr[j] = sW2b[(ks * 32 + hk + j) * 72 + d];
        zbar = MFMA16(a, bfr, zbar);
      }
    }
    if (w == 4) {
      f32x4 c = zf4;
#pragma unroll
      for (int ks = 0; ks < 8; ++ks) {
        short8 a = *(const short8*)&sXbb[fr * 264 + ks * 32 + hk];
        short8 bx = *(const short8*)&sX2b[fr * 264 + ks * 32 + hk];
        c = MFMA16(a, bx, c);
      }
#pragma unroll
      for (int qq = 0; qq < 4; ++qq) {
        const int i = half * 4 + qq, j = fr;
        const float v = (i >= j) ? sTok[i] * sLr[j] * (c[qq] + 1.0f) : 0.0f;
        sC2b[i * 24 + j] = f2bf(v);
      }
    }
    {
      const float tok15 = sTok[15];
      float lastj[8];
#pragma unroll
      for (int jj = 0; jj < 8; ++jj) lastj[jj] = tok15 * sLr[(hk + jj) & 15];
#pragma unroll
      for (int r = 0; r < 8; ++r) {
        const int T = w * 8 + r, dt = T >> 4, pt = T & 15;
        short8 af = zs8, bg = zs8;
        if (half < 2) {
#pragma unroll
          for (int jj = 0; jj < 8; ++jj)
            af[jj] = f2bf(bf2f(sX1b[(hk + jj) * 72 + dt * 16 + fr]) * lastj[jj]);
          bg = *(const short8*)&sG1c[(pt * 16 + fr) * 24 + hk];
        }
        f32x4 dl = MFMA16(af, bg, zf4);
        const int p = pt * 16 + fr;
        const int d0 = dt * 16 + half * 4;
        f32x4* wp = (f32x4*)&sW1c[p * 64 + (((d0 >> 2) ^ (p & 7)) << 2)];
        f32x4 cur = *wp;
        cur[0] -= dl[0]; cur[1] -= dl[1]; cur[2] -= dl[2]; cur[3] -= dl[3];
        *wp = cur;
      }
    }
    if (tid >= 256) {
      const int p = tid - 256;
      float s = 0.f;
#pragma unroll
      for (int j = 0; j < 16; ++j) s += sLr[j] * bf2f(sG1c[p * 24 + j]);
      sB1[p] -= sTok[15] * s;
    }
    __syncthreads();  // G

    // ---- ph7: Z2bar finalize (waves 0-3) | W2 update (waves 4-7)
    if (w < 4) {
      const int d = w * 16 + fr;
      short8 ac = zs8, bg = zs8;
      if (half < 2) {
        ac = *(const short8*)&sC2b[fr * 24 + hk];
        bg = *(const short8*)&sG2c[d * 24 + hk];
      }
      f32x4 corr = MFMA16(ac, bg, zf4);
      const float bb2 = sB2[d];
#pragma unroll
      for (int qq = 0; qq < 4; ++qq)
        sZ2f[(half * 4 + qq) * 68 + d] = zbar[qq] + bb2 - corr[qq];
    } else {
      const float tok15 = sTok[15];
      float lastj[8];
#pragma unroll
      for (int jj = 0; jj < 8; ++jj) lastj[jj] = tok15 * sLr[(hk + jj) & 15];
#pragma unroll
      for (int r = 0; r < 16; ++r) {
        const int T = (w - 4) * 16 + r, pt = T >> 2, dt = T & 3;
        short8 af = zs8, bg = zs8;
        if (half < 2) {
#pragma unroll
          for (int jj = 0; jj < 8; ++jj)
            af[jj] = f2bf(bf2f(sX2b[(hk + jj) * 264 + pt * 16 + fr]) * lastj[jj]);
          bg = *(const short8*)&sG2c[(dt * 16 + fr) * 24 + hk];
        }
        f32x4 dl = MFMA16(af, bg, zf4);
        const int p0 = pt * 16 + half * 4, d = dt * 16 + fr;
#pragma unroll
        for (int qq = 0; qq < 4; ++qq) {
          float* addr = &W2s[(long)(p0 + qq) * 64 + d];
          *addr = *addr - dl[qq];
        }
      }
    }
    __syncthreads();  // H

    // ---- ph8: XQW = XQ + ln_fwd(Z2_bar) (tid<256) | b2 update (tid 256-319)
    if (tid < 256) {
      const int i = tid >> 4, j4 = tid & 15;
      const f32x4 z = *(const f32x4*)&sZ2f[i * 68 + j4 * 4];
      float s1 = z[0] + z[1] + z[2] + z[3];
      float s2 = z[0] * z[0] + z[1] * z[1] + z[2] * z[2] + z[3] * z[3];
#pragma unroll
      for (int o = 8; o; o >>= 1) { s1 += __shfl_xor(s1, o, 16); s2 += __shfl_xor(s2, o, 16); }
      const float mu = s1 * (1.f / 64.f);
      const float rstd = rsqrtf(s2 * (1.f / 64.f) - mu * mu + 1e-6f);
      const f32x4 g = *(const f32x4*)&sLnw[j4 * 4];
      const f32x4 bb = *(const f32x4*)&sLnb[j4 * 4];
      f32x4 xq = *(const f32x4*)&Qb[gbase + (long)i * WIDTH + j4 * 4];
      f32x4 o4;
#pragma unroll
      for (int e = 0; e < 4; ++e) o4[e] = xq[e] + g[e] * ((z[e] - mu) * rstd) + bb[e];
      *(f32x4*)&Qb[gbase + (long)i * WIDTH + j4 * 4] = o4;
    } else if (tid < 320) {
      const int d = tid - 256;
      float s = 0.f;
#pragma unroll
      for (int j = 0; j < 16; ++j) s += sLr[j] * bf2f(sG2c[d * 24 + j]);
      sB2[d] -= sTok[15] * s;
    }
    __threadfence_block();
    __syncthreads();  // I
  }
}

// ---------------- epilogue: tmp = gelu(G) * ln_fwd(XQW, post_w, post_b)
__global__ __launch_bounds__(256) void epi_kernel(const float* __restrict__ X,
                                                  const float* __restrict__ G,
                                                  const float* __restrict__ pw,
                                                  const float* __restrict__ pb,
                                                  float* __restrict__ T) {
  __shared__ float red[8];
  const int t = blockIdx.x, tid = threadIdx.x;
  const long base = (long)t * 1024 + tid * 4;
  f32x4 x = *(const f32x4*)&X[base];
  float s1 = x[0] + x[1] + x[2] + x[3];
  float s2 = x[0] * x[0] + x[1] * x[1] + x[2] * x[2] + x[3] * x[3];
#pragma unroll
  for (int o = 32; o; o >>= 1) { s1 += __shfl_xor(s1, o, 64); s2 += __shfl_xor(s2, o, 64); }
  const int wv = tid >> 6, ln = tid & 63;
  if (ln == 0) { red[wv] = s1; red[4 + wv] = s2; }
  __syncthreads();
  s1 = red[0] + red[1] + red[2] + red[3];
  s2 = red[4] + red[5] + red[6] + red[7];
  const float mu = s1 * (1.f / 1024.f);
  const float rstd = rsqrtf(s2 * (1.f / 1024.f) - mu * mu + 1e-6f);
  f32x4 g = *(const f32x4*)&G[base];
  f32x4 w = *(const f32x4*)&pw[tid * 4];
  f32x4 bb = *(const f32x4*)&pb[tid * 4];
  f32x4 o4;
#pragma unroll
  for (int e = 0; e < 4; ++e) {
    float y = w[e] * ((x[e] - mu) * rstd) + bb[e];
    o4[e] = gelu_f(g[e]) * y;
  }
  *(f32x4*)&T[base] = o4;
}

extern "C" void kernel_launch(void* const* d_in, const int* in_sizes, int n_in,
                              void* d_out, int out_size, void* d_ws, size_t ws_size,
                              hipStream_t stream) {
  const float* hs  = (const float*)d_in[0];
  const float* Wq  = (const float*)d_in[1];
  const float* Wk  = (const float*)d_in[2];
  const float* Wv  = (const float*)d_in[3];
  const float* Wo  = (const float*)d_in[4];
  const float* Wg  = (const float*)d_in[5];
  const float* lrw = (const float*)d_in[6];
  const float* lrb = (const float*)d_in[7];
  const float* lti = (const float*)d_in[8];
  const float* nw  = (const float*)d_in[9];
  const float* nb  = (const float*)d_in[10];
  const float* W1  = (const float*)d_in[11];
  const float* b1  = (const float*)d_in[12];
  const float* W2  = (const float*)d_in[13];
  const float* b2  = (const float*)d_in[14];
  const float* pw  = (const float*)d_in[15];
  const float* pb  = (const float*)d_in[16];
  float* out = (float*)d_out;
  float* ws = (float*)d_ws;

  float* Qb  = ws;
  float* Kb  = ws + 8388608;
  float* Vb  = ws + 16777216;
  float* Gb  = ws + 25165824;
  float* LRb = ws + 33554432;
  float* W2S = ws + 33554432 + 131072;

  dim3 gg(128, 16);
  gemm_bt<<<gg, 256, 0, stream>>>(hs, Wq, Qb);
  gemm_bt<<<gg, 256, 0, stream>>>(hs, Wk, Kb);
  gemm_bt<<<gg, 256, 0, stream>>>(hs, Wv, Vb);
  gemm_bt<<<gg, 256, 0, stream>>>(hs, Wg, Gb);
  lr_kernel<<<8192, 256, 0, stream>>>(hs, lrw, lrb, LRb);
  scan_kernel<<<64, 512, 0, stream>>>(Qb, Kb, Vb, LRb, lti, nw, nb, W1, b1, W2, b2, W2S);
  epi_kernel<<<8192, 256, 0, stream>>>(Qb, Gb, pw, pb, Kb);
  gemm_bt<<<gg, 256, 0, stream>>>(Kb, Wo, out);
}

// Round 4
// 1749.375 us; speedup vs baseline: 25.5959x; 1.8921x over previous
//
#include <hip/hip_runtime.h>

#define WIDTH 1024
#define MBSZ 16
#define LLL 2048
#define NCHUNK 128

typedef __attribute__((ext_vector_type(4))) float f32x4;
typedef __attribute__((ext_vector_type(2))) float f32x2;
typedef __attribute__((ext_vector_type(8))) short short8;

#define MFMA16(a, b, c) __builtin_amdgcn_mfma_f32_16x16x32_bf16((a), (b), (c), 0, 0, 0)

__device__ __forceinline__ short f2bf(float f) {
  unsigned u = __float_as_uint(f);
  u = (u + 0x7FFFu + ((u >> 16) & 1u)) >> 16;  // RNE f32->bf16
  return (short)u;
}
__device__ __forceinline__ float bf2f(short s) {
  return __uint_as_float(((unsigned)(unsigned short)s) << 16);
}
// e^{2u(x)} with u = 0.79788456 x (1 + 0.044715 x^2);  2*log2e*0.79788456 = 2.30220776
__device__ __forceinline__ float fast_e2u(float x) {
  return __builtin_amdgcn_exp2f(x * (2.30220776f + 0.10294322f * x * x));
}
__device__ __forceinline__ float gelu_f(float x) {
  float e = fast_e2u(x);
  return x * (1.0f - __builtin_amdgcn_rcpf(e + 1.0f));
}
__device__ __forceinline__ float gelu_bwd_f(float x) {
  float e = fast_e2u(x);
  float r = __builtin_amdgcn_rcpf(e + 1.0f);
  return 2.0f * x * r * (1.0f - r) * (0.79788456f + 0.1070322243f * x * x) + (1.0f - r);
}

// ---------------- C[8192][1024] = A[8192][1024] @ W[1024][1024]^T (bf16 MFMA, fp32 in/out)
__global__ __launch_bounds__(256) void gemm_bt(const float* __restrict__ A,
                                               const float* __restrict__ W,
                                               float* __restrict__ C) {
  __shared__ __align__(16) short sA[64][40];
  __shared__ __align__(16) short sB[64][40];
  const int tid = threadIdx.x;
  const int m0 = blockIdx.x * 64, n0 = blockIdx.y * 64;
  const int srow = tid >> 2, sk = (tid & 3) * 8;
  const int wv = tid >> 6, ln = tid & 63;
  const int fr = ln & 15, kh = (ln >> 4) * 8;
  f32x4 acc[4];
#pragma unroll
  for (int s = 0; s < 4; ++s) acc[s] = (f32x4){0.f, 0.f, 0.f, 0.f};
  const float* ga = A + (long)(m0 + srow) * 1024 + sk;
  const float* gw = W + (long)(n0 + srow) * 1024 + sk;
  for (int k0 = 0; k0 < 1024; k0 += 32) {
    f32x4 a0 = *(const f32x4*)(ga + k0);
    f32x4 a1 = *(const f32x4*)(ga + k0 + 4);
    f32x4 w0 = *(const f32x4*)(gw + k0);
    f32x4 w1 = *(const f32x4*)(gw + k0 + 4);
    short8 pa, pw;
    pa[0] = f2bf(a0[0]); pa[1] = f2bf(a0[1]); pa[2] = f2bf(a0[2]); pa[3] = f2bf(a0[3]);
    pa[4] = f2bf(a1[0]); pa[5] = f2bf(a1[1]); pa[6] = f2bf(a1[2]); pa[7] = f2bf(a1[3]);
    pw[0] = f2bf(w0[0]); pw[1] = f2bf(w0[1]); pw[2] = f2bf(w0[2]); pw[3] = f2bf(w0[3]);
    pw[4] = f2bf(w1[0]); pw[5] = f2bf(w1[1]); pw[6] = f2bf(w1[2]); pw[7] = f2bf(w1[3]);
    *(short8*)&sA[srow][sk] = pa;
    *(short8*)&sB[srow][sk] = pw;
    __syncthreads();
    short8 af = *(const short8*)&sA[wv * 16 + fr][kh];
#pragma unroll
    for (int s = 0; s < 4; ++s) {
      short8 bf8 = *(const short8*)&sB[s * 16 + fr][kh];
      acc[s] = MFMA16(af, bf8, acc[s]);
    }
    __syncthreads();
  }
  const int orow = m0 + wv * 16 + (ln >> 4) * 4;
#pragma unroll
  for (int s = 0; s < 4; ++s)
#pragma unroll
    for (int q = 0; q < 4; ++q)
      C[(long)(orow + q) * 1024 + n0 + s * 16 + fr] = acc[s][q];
}

// ---------------- lr_eta[b,h,t] = sigmoid(hs[t]·lr_w[h] + lr_b[h]) / 64
__global__ __launch_bounds__(256) void lr_kernel(const float* __restrict__ hs,
                                                 const float* __restrict__ lrw,
                                                 const float* __restrict__ lrb,
                                                 float* __restrict__ out) {
  __shared__ __align__(16) float row[1024];
  const int t = blockIdx.x, tid = threadIdx.x;
  *(f32x4*)&row[tid * 4] = *(const f32x4*)&hs[(long)t * 1024 + tid * 4];
  __syncthreads();
  const int hh = tid >> 4, j = tid & 15;
  const float* wrow = lrw + hh * 1024;
  float s = 0.f;
#pragma unroll 4
  for (int m = 0; m < 16; ++m) {
    const int c = j * 4 + m * 64;
    f32x4 x = *(const f32x4*)&row[c];
    f32x4 w = *(const f32x4*)&wrow[c];
    s += x[0] * w[0] + x[1] * w[1] + x[2] * w[2] + x[3] * w[3];
  }
#pragma unroll
  for (int o = 8; o; o >>= 1) s += __shfl_xor(s, o, 16);
  if (j == 0) {
    const float v = s + lrb[hh];
    const float sg = 1.f / (1.f + expf(-v));
    const int b = t >> 11, tr = t & 2047;
    out[((b << 4) + hh) * 2048 + tr] = sg * (1.f / 64.f);
  }
}

// ---------------- sequential TTT scan: one block of 512 per (b,h)
// bf16 W1/W2 persistent in LDS (frag layouts), fp32 masters in global (thread-private RMW)
__global__ __launch_bounds__(512, 2) void scan_kernel(
    float* __restrict__ Qb, const float* __restrict__ Kb, const float* __restrict__ Vb,
    const float* __restrict__ LRb, const float* __restrict__ lti,
    const float* __restrict__ nw, const float* __restrict__ nb,
    const float* __restrict__ W1in, const float* __restrict__ b1in,
    const float* __restrict__ W2in, const float* __restrict__ b2in,
    float* __restrict__ W1S_, float* __restrict__ W2S_) {
  __shared__ __align__(16) short sW1b[256 * 72];   // bf16 W1[p][d]
  __shared__ __align__(16) short sW2dp[64 * 264];  // bf16 W2[d][p^sw], sw=((d>>3)&3)<<3
  __shared__ __align__(16) short la1T[64 * 24];    // bf16 lastj[j]*X1[j][d] as [d][j]
  __shared__ __align__(16) short la2T[256 * 24];   // bf16 lastj[j]*X2[j][p] as [p][j]
  __shared__ __align__(16) short sX1b[16 * 72];    // bf16 X1[i][d]
  __shared__ __align__(16) short sXQb[16 * 72];    // bf16 XQ[i][d]
  __shared__ __align__(16) float sTg[16 * 72];     // f32 (V-K)[i][d]
  __shared__ __align__(16) short sX2b[16 * 264];   // bf16 X2[i][p]
  __shared__ __align__(16) short sXbb[16 * 264];   // bf16 X2_bar[i][p]
  __shared__ __align__(16) short sG1c[256 * 24];   // bf16 gZ1 col-major [p][j]
  __shared__ __align__(16) short sG2b[16 * 72];    // bf16 gZ2[i][d]
  __shared__ __align__(16) short sG2c[64 * 24];    // bf16 gZ2 col-major [d][j]
  __shared__ __align__(16) float sZ2f[16 * 68];    // f32 Z2 / Z2_bar
  __shared__ __align__(16) short sC1b[16 * 24];    // bf16 C1'[i][j]
  __shared__ __align__(16) short sC2b[16 * 24];    // bf16 C2'[i][j]
  __shared__ __align__(16) float sB1[256];
  __shared__ __align__(16) float sB2[64];
  __shared__ float sLr[16];
  __shared__ float sTok[16];
  __shared__ __align__(16) float sLnw[64];
  __shared__ __align__(16) float sLnb[64];

  const int bh = blockIdx.x, b = bh >> 4, h = bh & 15;
  const int tid = threadIdx.x;
  const int w = tid >> 6, ln = tid & 63;
  const int fr = ln & 15, half = ln >> 4, hk = half * 8;
  const int nt0 = 2 * w;

  float* __restrict__ W1S = W1S_ + (long)bh * 16384;  // fp32 master [p][64]
  float* __restrict__ W2S = W2S_ + (long)bh * 16384;  // fp32 master [d][256]

  // preamble: masters + bf16 LDS copies
  for (int e = tid; e < 16384; e += 512) {
    {  // W1in layout [d=64][p=256]
      const int d = e >> 8, p = e & 255;
      const float v = W1in[h * 16384 + e];
      W1S[p * 64 + d] = v;
      sW1b[p * 72 + d] = f2bf(v);
    }
    {  // W2in layout [p=256][d=64]
      const int p = e >> 6, d = e & 63;
      const float v = W2in[h * 16384 + e];
      W2S[d * 256 + p] = v;
      sW2dp[d * 264 + (p ^ (((d >> 3) & 3) << 3))] = f2bf(v);
    }
  }
  if (tid < 256) sB1[tid] = b1in[h * 256 + tid];
  if (tid < 64) { sB2[tid] = b2in[h * 64 + tid]; sLnw[tid] = nw[h * 64 + tid]; sLnb[tid] = nb[h * 64 + tid]; }
  if (tid < 16) sTok[tid] = fmaxf(1.0f / (float)(tid + 1) + lti[tid], 0.0f);

  const f32x4 zf4 = (f32x4){0.f, 0.f, 0.f, 0.f};
  short8 zs8;
#pragma unroll
  for (int j = 0; j < 8; ++j) zs8[j] = 0;

  // chunk-input prefetch (regs)
  const int pf_i = tid >> 5;
  const int pf_d = (tid & 31) * 2;
  f32x2 pk, pq, pv;
  float plr = 0.f;
  {
    const long a0 = ((long)(b * LLL + pf_i)) * WIDTH + h * 64 + pf_d;
    pk = *(const f32x2*)&Kb[a0];
    pq = *(const f32x2*)&Qb[a0];
    pv = *(const f32x2*)&Vb[a0];
    if (tid < 16) plr = LRb[(long)bh * 2048 + tid];
  }

  for (int n = 0; n < NCHUNK; ++n) {
    const long gbase = ((long)(b * LLL + n * MBSZ)) * WIDTH + h * 64;

    // ---- commit prefetched chunk to LDS
    {
      const unsigned uk = ((unsigned)(unsigned short)f2bf(pk[0])) | (((unsigned)(unsigned short)f2bf(pk[1])) << 16);
      const unsigned uq = ((unsigned)(unsigned short)f2bf(pq[0])) | (((unsigned)(unsigned short)f2bf(pq[1])) << 16);
      *(unsigned*)&sX1b[pf_i * 72 + pf_d] = uk;
      *(unsigned*)&sXQb[pf_i * 72 + pf_d] = uq;
      sTg[pf_i * 72 + pf_d] = pv[0] - pk[0];
      sTg[pf_i * 72 + pf_d + 1] = pv[1] - pk[1];
      if (tid < 16) sLr[tid] = plr;
    }
    __syncthreads();  // A

    // ---- B: Z1 & XQ@W1 (MFMA) -> z1/q1; X2->LDS; la1T; C1 (wave 0)
    short8 aX1[2], aXQ[2];
    aX1[0] = *(const short8*)&sX1b[fr * 72 + hk];
    aX1[1] = *(const short8*)&sX1b[fr * 72 + 32 + hk];
    aXQ[0] = *(const short8*)&sXQb[fr * 72 + hk];
    aXQ[1] = *(const short8*)&sXQb[fr * 72 + 32 + hk];
    f32x4 z1[2], q1[2];
    float b1p[2];
#pragma unroll
    for (int t = 0; t < 2; ++t) {
      const int p = (nt0 + t) * 16 + fr;
      z1[t] = zf4; q1[t] = zf4;
#pragma unroll
      for (int ks = 0; ks < 2; ++ks) {
        short8 bw = *(const short8*)&sW1b[p * 72 + ks * 32 + hk];
        z1[t] = MFMA16(aX1[ks], bw, z1[t]);
        q1[t] = MFMA16(aXQ[ks], bw, q1[t]);
      }
      b1p[t] = sB1[p];
#pragma unroll
      for (int qq = 0; qq < 4; ++qq) {
        z1[t][qq] += b1p[t];
        sX2b[(half * 4 + qq) * 264 + p] = f2bf(gelu_f(z1[t][qq]));
      }
    }
    {
      const float tok15 = sTok[15];
#pragma unroll
      for (int k = 0; k < 2; ++k) {
        const int e = tid + k * 512, d = e >> 4, j = e & 15;
        la1T[d * 24 + j] = f2bf(bf2f(sX1b[j * 72 + d]) * (tok15 * sLr[j]));
      }
    }
    if (w == 0) {
      f32x4 c = MFMA16(aXQ[0], aX1[0], zf4);
      c = MFMA16(aXQ[1], aX1[1], c);
#pragma unroll
      for (int qq = 0; qq < 4; ++qq) {
        const int i = half * 4 + qq, j = fr;
        sC1b[i * 24 + j] = f2bf((i >= j) ? sTok[i] * sLr[j] * (c[qq] + 1.0f) : 0.0f);
      }
    }
    __syncthreads();  // B

    // ---- C: Z2 = X2@W2 + b2 (waves 0-3) | la2T (waves 4-7)
    float bb2old = 0.f;
    if (w < 4) {
      const int d = w * 16 + fr;
      const int sw = ((d >> 3) & 3) << 3;
      f32x4 za = zf4, zb = zf4;
#pragma unroll
      for (int ks = 0; ks < 4; ++ks) {
        short8 a = *(const short8*)&sX2b[fr * 264 + ks * 32 + hk];
        short8 bfr = *(const short8*)&sW2dp[d * 264 + ((ks * 32 + hk) ^ sw)];
        za = MFMA16(a, bfr, za);
      }
#pragma unroll
      for (int ks = 4; ks < 8; ++ks) {
        short8 a = *(const short8*)&sX2b[fr * 264 + ks * 32 + hk];
        short8 bfr = *(const short8*)&sW2dp[d * 264 + ((ks * 32 + hk) ^ sw)];
        zb = MFMA16(a, bfr, zb);
      }
      bb2old = sB2[d];
#pragma unroll
      for (int qq = 0; qq < 4; ++qq)
        sZ2f[(half * 4 + qq) * 68 + d] = za[qq] + zb[qq] + bb2old;
    } else {
      const int t0 = tid - 256;
      const float tok15 = sTok[15];
#pragma unroll
      for (int k = 0; k < 16; ++k) {
        const int e = t0 + k * 256, pp = e >> 4, j = e & 15;
        la2T[pp * 24 + j] = f2bf(bf2f(sX2b[j * 264 + pp]) * (tok15 * sLr[j]));
      }
    }
    __syncthreads();  // C

    // ---- D: gZ2 = ln_l2_bwd(Z2, V-K)  (tid<256)
    if (tid < 256) {
      const int i = tid >> 4, j4 = tid & 15;
      const f32x4 z = *(const f32x4*)&sZ2f[i * 68 + j4 * 4];
      float s1 = z[0] + z[1] + z[2] + z[3];
      float s2 = z[0] * z[0] + z[1] * z[1] + z[2] * z[2] + z[3] * z[3];
#pragma unroll
      for (int o = 8; o; o >>= 1) { s1 += __shfl_xor(s1, o, 16); s2 += __shfl_xor(s2, o, 16); }
      const float mu = s1 * (1.f / 64.f);
      const float rstd = rsqrtf(s2 * (1.f / 64.f) - mu * mu + 1e-6f);
      const f32x4 g = *(const f32x4*)&sLnw[j4 * 4];
      const f32x4 bb = *(const f32x4*)&sLnb[j4 * 4];
      const f32x4 tg = *(const f32x4*)&sTg[i * 72 + j4 * 4];
      f32x4 xh, gx;
      float a1 = 0.f, a2 = 0.f;
#pragma unroll
      for (int e = 0; e < 4; ++e) {
        xh[e] = (z[e] - mu) * rstd;
        gx[e] = (g[e] * xh[e] + bb[e] - tg[e]) * g[e];
        a1 += gx[e]; a2 += gx[e] * xh[e];
      }
#pragma unroll
      for (int o = 8; o; o >>= 1) { a1 += __shfl_xor(a1, o, 16); a2 += __shfl_xor(a2, o, 16); }
      const float m1 = a1 * (1.f / 64.f), m2 = a2 * (1.f / 64.f);
#pragma unroll
      for (int e = 0; e < 4; ++e) {
        const int d = j4 * 4 + e;
        const short v = f2bf((gx[e] - m1 - xh[e] * m2) * rstd);
        sG2b[i * 72 + d] = v;
        sG2c[d * 24 + i] = v;
      }
    }
    __syncthreads();  // D

    // ---- E: gZ1 = (gZ2@W2^T)*gelu_bwd(Z1) -> sG1c (all waves) | b2 update (tid<64)
    {
      short8 aG2[2];
      aG2[0] = *(const short8*)&sG2b[fr * 72 + hk];
      aG2[1] = *(const short8*)&sG2b[fr * 72 + 32 + hk];
#pragma unroll
      for (int t = 0; t < 2; ++t) {
        const int p = (nt0 + t) * 16 + fr;
        f32x4 g = zf4;
#pragma unroll
        for (int ks = 0; ks < 2; ++ks) {
          short8 bw;
#pragma unroll
          for (int jj = 0; jj < 8; ++jj) {
            const int d = ks * 32 + hk + jj;
            bw[jj] = sW2dp[d * 264 + (p ^ (((d >> 3) & 3) << 3))];
          }
          g = MFMA16(aG2[ks], bw, g);
        }
#pragma unroll
        for (int qq = 0; qq < 4; ++qq)
          sG1c[p * 24 + half * 4 + qq] = f2bf(g[qq] * gelu_bwd_f(z1[t][qq]));
      }
    }
    if (tid < 64) {
      float s = 0.f;
#pragma unroll
      for (int j = 0; j < 16; ++j) s += sLr[j] * bf2f(sG2c[tid * 24 + j]);
      sB2[tid] -= sTok[15] * s;
    }
    __syncthreads();  // E

    // ---- F: X2_bar (all waves) | W1 update (all waves) | b1 update (tid<256)
    {
      short8 ac = zs8;
      if (half < 2) ac = *(const short8*)&sC1b[fr * 24 + hk];
#pragma unroll
      for (int t = 0; t < 2; ++t) {
        const int p = (nt0 + t) * 16 + fr;
        short8 bg = zs8;
        if (half < 2) bg = *(const short8*)&sG1c[p * 24 + hk];
        f32x4 corr = MFMA16(ac, bg, zf4);
#pragma unroll
        for (int qq = 0; qq < 4; ++qq)
          sXbb[(half * 4 + qq) * 264 + p] = f2bf(gelu_f(q1[t][qq] + b1p[t] - corr[qq]));
      }
    }
    {
#pragma unroll
      for (int r = 0; r < 8; ++r) {
        const int T = w * 8 + r, dt = T >> 4, pt = T & 15;
        short8 af = zs8, bg = zs8;
        if (half < 2) {
          af = *(const short8*)&la1T[(dt * 16 + fr) * 24 + hk];
          bg = *(const short8*)&sG1c[(pt * 16 + fr) * 24 + hk];
        }
        f32x4 dl = MFMA16(af, bg, zf4);
        const int pp = pt * 16 + fr, d0 = dt * 16 + half * 4;
        float* mp = &W1S[(long)pp * 64 + d0];
        f32x4 cur = *(const f32x4*)mp;
        cur[0] -= dl[0]; cur[1] -= dl[1]; cur[2] -= dl[2]; cur[3] -= dl[3];
        *(f32x4*)mp = cur;
#pragma unroll
        for (int qq = 0; qq < 4; ++qq) sW1b[pp * 72 + d0 + qq] = f2bf(cur[qq]);
      }
    }
    if (tid < 256) {
      float s = 0.f;
#pragma unroll
      for (int j = 0; j < 16; ++j) s += sLr[j] * bf2f(sG1c[tid * 24 + j]);
      sB1[tid] -= sTok[15] * s;
    }
    __syncthreads();  // F

    // ---- G: prefetch issue; Z2bar partial (w0-3) | C2 (w4)
    {
      const int nn = (n + 1 < NCHUNK) ? n + 1 : n;
      const long a1 = ((long)(b * LLL + nn * MBSZ + pf_i)) * WIDTH + h * 64 + pf_d;
      pk = *(const f32x2*)&Kb[a1];
      pq = *(const f32x2*)&Qb[a1];
      pv = *(const f32x2*)&Vb[a1];
      if (tid < 16) plr = LRb[(long)bh * 2048 + nn * MBSZ + tid];
    }
    f32x4 zbar = zf4;
    if (w < 4) {
      const int d = w * 16 + fr;
      const int sw = ((d >> 3) & 3) << 3;
      f32x4 za = zf4, zb = zf4;
#pragma unroll
      for (int ks = 0; ks < 4; ++ks) {
        short8 a = *(const short8*)&sXbb[fr * 264 + ks * 32 + hk];
        short8 bfr = *(const short8*)&sW2dp[d * 264 + ((ks * 32 + hk) ^ sw)];
        za = MFMA16(a, bfr, za);
      }
#pragma unroll
      for (int ks = 4; ks < 8; ++ks) {
        short8 a = *(const short8*)&sXbb[fr * 264 + ks * 32 + hk];
        short8 bfr = *(const short8*)&sW2dp[d * 264 + ((ks * 32 + hk) ^ sw)];
        zb = MFMA16(a, bfr, zb);
      }
      zbar[0] = za[0] + zb[0]; zbar[1] = za[1] + zb[1];
      zbar[2] = za[2] + zb[2]; zbar[3] = za[3] + zb[3];
    } else if (w == 4) {
      f32x4 c = zf4;
#pragma unroll
      for (int ks = 0; ks < 8; ++ks) {
        short8 a = *(const short8*)&sXbb[fr * 264 + ks * 32 + hk];
        short8 bx = *(const short8*)&sX2b[fr * 264 + ks * 32 + hk];
        c = MFMA16(a, bx, c);
      }
#pragma unroll
      for (int qq = 0; qq < 4; ++qq) {
        const int i = half * 4 + qq, j = fr;
        sC2b[i * 24 + j] = f2bf((i >= j) ? sTok[i] * sLr[j] * (c[qq] + 1.0f) : 0.0f);
      }
    }
    __syncthreads();  // G

    // ---- H: Z2bar finalize (w0-3) | W2 update (w4-7)
    if (w < 4) {
      const int d = w * 16 + fr;
      short8 ac = zs8, bg = zs8;
      if (half < 2) {
        ac = *(const short8*)&sC2b[fr * 24 + hk];
        bg = *(const short8*)&sG2c[d * 24 + hk];
      }
      f32x4 corr = MFMA16(ac, bg, zf4);
#pragma unroll
      for (int qq = 0; qq < 4; ++qq)
        sZ2f[(half * 4 + qq) * 68 + d] = zbar[qq] + bb2old - corr[qq];
    } else {
#pragma unroll
      for (int r = 0; r < 16; ++r) {
        const int T = (w - 4) * 16 + r, pt = T >> 2, dt = T & 3;
        short8 af = zs8, bg = zs8;
        if (half < 2) {
          af = *(const short8*)&la2T[(pt * 16 + fr) * 24 + hk];
          bg = *(const short8*)&sG2c[(dt * 16 + fr) * 24 + hk];
        }
        f32x4 dl = MFMA16(af, bg, zf4);
        const int dd = dt * 16 + fr, p0 = pt * 16 + half * 4;
        float* mp = &W2S[(long)dd * 256 + p0];
        f32x4 cur = *(const f32x4*)mp;
        cur[0] -= dl[0]; cur[1] -= dl[1]; cur[2] -= dl[2]; cur[3] -= dl[3];
        *(f32x4*)mp = cur;
        const int pb = p0 ^ (((dd >> 3) & 3) << 3);
#pragma unroll
        for (int qq = 0; qq < 4; ++qq) sW2dp[dd * 264 + pb + qq] = f2bf(cur[qq]);
      }
    }
    __syncthreads();  // H

    // ---- I: XQW = XQ + ln_fwd(Z2_bar) -> Qb  (tid<256); no barrier (A covers it)
    if (tid < 256) {
      const int i = tid >> 4, j4 = tid & 15;
      const f32x4 z = *(const f32x4*)&sZ2f[i * 68 + j4 * 4];
      float s1 = z[0] + z[1] + z[2] + z[3];
      float s2 = z[0] * z[0] + z[1] * z[1] + z[2] * z[2] + z[3] * z[3];
#pragma unroll
      for (int o = 8; o; o >>= 1) { s1 += __shfl_xor(s1, o, 16); s2 += __shfl_xor(s2, o, 16); }
      const float mu = s1 * (1.f / 64.f);
      const float rstd = rsqrtf(s2 * (1.f / 64.f) - mu * mu + 1e-6f);
      const f32x4 g = *(const f32x4*)&sLnw[j4 * 4];
      const f32x4 bb = *(const f32x4*)&sLnb[j4 * 4];
      f32x4 xq = *(const f32x4*)&Qb[gbase + (long)i * WIDTH + j4 * 4];
      f32x4 o4;
#pragma unroll
      for (int e = 0; e < 4; ++e) o4[e] = xq[e] + g[e] * ((z[e] - mu) * rstd) + bb[e];
      *(f32x4*)&Qb[gbase + (long)i * WIDTH + j4 * 4] = o4;
    }
    __syncthreads();  // I (protects sZ2f/sX1b etc. for next chunk)
  }
}

// ---------------- epilogue: tmp = gelu(G) * ln_fwd(XQW, post_w, post_b)
__global__ __launch_bounds__(256) void epi_kernel(const float* __restrict__ X,
                                                  const float* __restrict__ G,
                                                  const float* __restrict__ pw,
                                                  const float* __restrict__ pb,
                                                  float* __restrict__ T) {
  __shared__ float red[8];
  const int t = blockIdx.x, tid = threadIdx.x;
  const long base = (long)t * 1024 + tid * 4;
  f32x4 x = *(const f32x4*)&X[base];
  float s1 = x[0] + x[1] + x[2] + x[3];
  float s2 = x[0] * x[0] + x[1] * x[1] + x[2] * x[2] + x[3] * x[3];
#pragma unroll
  for (int o = 32; o; o >>= 1) { s1 += __shfl_xor(s1, o, 64); s2 += __shfl_xor(s2, o, 64); }
  const int wv = tid >> 6, ln = tid & 63;
  if (ln == 0) { red[wv] = s1; red[4 + wv] = s2; }
  __syncthreads();
  s1 = red[0] + red[1] + red[2] + red[3];
  s2 = red[4] + red[5] + red[6] + red[7];
  const float mu = s1 * (1.f / 1024.f);
  const float rstd = rsqrtf(s2 * (1.f / 1024.f) - mu * mu + 1e-6f);
  f32x4 g = *(const f32x4*)&G[base];
  f32x4 w = *(const f32x4*)&pw[tid * 4];
  f32x4 bb = *(const f32x4*)&pb[tid * 4];
  f32x4 o4;
#pragma unroll
  for (int e = 0; e < 4; ++e) {
    float y = w[e] * ((x[e] - mu) * rstd) + bb[e];
    o4[e] = gelu_f(g[e]) * y;
  }
  *(f32x4*)&T[base] = o4;
}

extern "C" void kernel_launch(void* const* d_in, const int* in_sizes, int n_in,
                              void* d_out, int out_size, void* d_ws, size_t ws_size,
                              hipStream_t stream) {
  const float* hs  = (const float*)d_in[0];
  const float* Wq  = (const float*)d_in[1];
  const float* Wk  = (const float*)d_in[2];
  const float* Wv  = (const float*)d_in[3];
  const float* Wo  = (const float*)d_in[4];
  const float* Wg  = (const float*)d_in[5];
  const float* lrw = (const float*)d_in[6];
  const float* lrb = (const float*)d_in[7];
  const float* lti = (const float*)d_in[8];
  const float* nw  = (const float*)d_in[9];
  const float* nb  = (const float*)d_in[10];
  const float* W1  = (const float*)d_in[11];
  const float* b1  = (const float*)d_in[12];
  const float* W2  = (const float*)d_in[13];
  const float* b2  = (const float*)d_in[14];
  const float* pw  = (const float*)d_in[15];
  const float* pb  = (const float*)d_in[16];
  float* out = (float*)d_out;
  float* ws = (float*)d_ws;

  float* Qb  = ws;
  float* Kb  = ws + 8388608;
  float* Vb  = ws + 16777216;
  float* Gb  = ws + 25165824;
  float* LRb = ws + 33554432;
  // fp32 W1/W2 masters live in d_out (dead until the final GEMM overwrites it)
  float* W2S = out;             // 64 * 16384 floats
  float* W1S = out + 1048576;   // 64 * 16384 floats

  dim3 gg(128, 16);
  gemm_bt<<<gg, 256, 0, stream>>>(hs, Wq, Qb);
  gemm_bt<<<gg, 256, 0, stream>>>(hs, Wk, Kb);
  gemm_bt<<<gg, 256, 0, stream>>>(hs, Wv, Vb);
  gemm_bt<<<gg, 256, 0, stream>>>(hs, Wg, Gb);
  lr_kernel<<<8192, 256, 0, stream>>>(hs, lrw, lrb, LRb);
  scan_kernel<<<64, 512, 0, stream>>>(Qb, Kb, Vb, LRb, lti, nw, nb, W1, b1, W2, b2, W1S, W2S);
  epi_kernel<<<8192, 256, 0, stream>>>(Qb, Gb, pw, pb, Kb);
  gemm_bt<<<gg, 256, 0, stream>>>(Kb, Wo, out);
}

// Round 5
// 1300.766 us; speedup vs baseline: 34.4235x; 1.3449x over previous
//
#include <hip/hip_runtime.h>

#define WIDTH 1024
#define MBSZ 16
#define LLL 2048
#define NCHUNK 128

typedef __attribute__((ext_vector_type(4))) float f32x4;
typedef __attribute__((ext_vector_type(2))) float f32x2;
typedef __attribute__((ext_vector_type(8))) short short8;

#define MFMA16(a, b, c) __builtin_amdgcn_mfma_f32_16x16x32_bf16((a), (b), (c), 0, 0, 0)

__device__ __forceinline__ short f2bf(float f) {
  unsigned u = __float_as_uint(f);
  u = (u + 0x7FFFu + ((u >> 16) & 1u)) >> 16;  // RNE f32->bf16
  return (short)u;
}
__device__ __forceinline__ float bf2f(short s) {
  return __uint_as_float(((unsigned)(unsigned short)s) << 16);
}
// e^{2u(x)} with u = 0.79788456 x (1 + 0.044715 x^2);  2*log2e*0.79788456 = 2.30220776
__device__ __forceinline__ float fast_e2u(float x) {
  return __builtin_amdgcn_exp2f(x * (2.30220776f + 0.10294322f * x * x));
}
__device__ __forceinline__ float gelu_f(float x) {
  float e = fast_e2u(x);
  return x * (1.0f - __builtin_amdgcn_rcpf(e + 1.0f));
}
__device__ __forceinline__ float gelu_bwd_f(float x) {
  float e = fast_e2u(x);
  float r = __builtin_amdgcn_rcpf(e + 1.0f);
  return 2.0f * x * r * (1.0f - r) * (0.79788456f + 0.1070322243f * x * x) + (1.0f - r);
}

// ---------------- C[8192][1024] = A[8192][1024] @ W[1024][1024]^T (bf16 MFMA, fp32 in/out)
__global__ __launch_bounds__(256) void gemm_bt(const float* __restrict__ A,
                                               const float* __restrict__ W,
                                               float* __restrict__ C) {
  __shared__ __align__(16) short sA[64][40];
  __shared__ __align__(16) short sB[64][40];
  const int tid = threadIdx.x;
  const int m0 = blockIdx.x * 64, n0 = blockIdx.y * 64;
  const int srow = tid >> 2, sk = (tid & 3) * 8;
  const int wv = tid >> 6, ln = tid & 63;
  const int fr = ln & 15, kh = (ln >> 4) * 8;
  f32x4 acc[4];
#pragma unroll
  for (int s = 0; s < 4; ++s) acc[s] = (f32x4){0.f, 0.f, 0.f, 0.f};
  const float* ga = A + (long)(m0 + srow) * 1024 + sk;
  const float* gw = W + (long)(n0 + srow) * 1024 + sk;
  for (int k0 = 0; k0 < 1024; k0 += 32) {
    f32x4 a0 = *(const f32x4*)(ga + k0);
    f32x4 a1 = *(const f32x4*)(ga + k0 + 4);
    f32x4 w0 = *(const f32x4*)(gw + k0);
    f32x4 w1 = *(const f32x4*)(gw + k0 + 4);
    short8 pa, pw;
    pa[0] = f2bf(a0[0]); pa[1] = f2bf(a0[1]); pa[2] = f2bf(a0[2]); pa[3] = f2bf(a0[3]);
    pa[4] = f2bf(a1[0]); pa[5] = f2bf(a1[1]); pa[6] = f2bf(a1[2]); pa[7] = f2bf(a1[3]);
    pw[0] = f2bf(w0[0]); pw[1] = f2bf(w0[1]); pw[2] = f2bf(w0[2]); pw[3] = f2bf(w0[3]);
    pw[4] = f2bf(w1[0]); pw[5] = f2bf(w1[1]); pw[6] = f2bf(w1[2]); pw[7] = f2bf(w1[3]);
    *(short8*)&sA[srow][sk] = pa;
    *(short8*)&sB[srow][sk] = pw;
    __syncthreads();
    short8 af = *(const short8*)&sA[wv * 16 + fr][kh];
#pragma unroll
    for (int s = 0; s < 4; ++s) {
      short8 bf8 = *(const short8*)&sB[s * 16 + fr][kh];
      acc[s] = MFMA16(af, bf8, acc[s]);
    }
    __syncthreads();
  }
  const int orow = m0 + wv * 16 + (ln >> 4) * 4;
#pragma unroll
  for (int s = 0; s < 4; ++s)
#pragma unroll
    for (int q = 0; q < 4; ++q)
      C[(long)(orow + q) * 1024 + n0 + s * 16 + fr] = acc[s][q];
}

// ---------------- lr_eta[b,h,t] = sigmoid(hs[t]·lr_w[h] + lr_b[h]) / 64
__global__ __launch_bounds__(256) void lr_kernel(const float* __restrict__ hs,
                                                 const float* __restrict__ lrw,
                                                 const float* __restrict__ lrb,
                                                 float* __restrict__ out) {
  __shared__ __align__(16) float row[1024];
  const int t = blockIdx.x, tid = threadIdx.x;
  *(f32x4*)&row[tid * 4] = *(const f32x4*)&hs[(long)t * 1024 + tid * 4];
  __syncthreads();
  const int hh = tid >> 4, j = tid & 15;
  const float* wrow = lrw + hh * 1024;
  float s = 0.f;
#pragma unroll 4
  for (int m = 0; m < 16; ++m) {
    const int c = j * 4 + m * 64;
    f32x4 x = *(const f32x4*)&row[c];
    f32x4 w = *(const f32x4*)&wrow[c];
    s += x[0] * w[0] + x[1] * w[1] + x[2] * w[2] + x[3] * w[3];
  }
#pragma unroll
  for (int o = 8; o; o >>= 1) s += __shfl_xor(s, o, 16);
  if (j == 0) {
    const float v = s + lrb[hh];
    const float sg = 1.f / (1.f + expf(-v));
    const int b = t >> 11, tr = t & 2047;
    out[((b << 4) + hh) * 2048 + tr] = sg * (1.f / 64.f);
  }
}

// ---------------- sequential TTT scan: one block of 512 per (b,h)
// bf16 W1/W2 in LDS (frag layouts); fp32 masters in REGISTERS (stationary fragment ownership)
__global__ __launch_bounds__(512, 2) void scan_kernel(
    float* __restrict__ Qb, const float* __restrict__ Kb, const float* __restrict__ Vb,
    const float* __restrict__ LRb, const float* __restrict__ lti,
    const float* __restrict__ nw, const float* __restrict__ nb,
    const float* __restrict__ W1in, const float* __restrict__ b1in,
    const float* __restrict__ W2in, const float* __restrict__ b2in) {
  __shared__ __align__(16) short sW1b[256 * 72];   // bf16 W1[p][d]
  __shared__ __align__(16) short sW2dp[64 * 264];  // bf16 W2[d][p^sw], sw=((d>>3)&3)<<3
  __shared__ __align__(16) short la1T[64 * 24];    // bf16 lastj[j]*X1[j][d] as [d][j]
  __shared__ __align__(16) short la2T[256 * 24];   // bf16 lastj[j]*X2[j][p] as [p][j]
  __shared__ __align__(16) short sX1b[16 * 72];    // bf16 X1[i][d]
  __shared__ __align__(16) short sXQb[16 * 72];    // bf16 XQ[i][d]
  __shared__ __align__(16) float sTg[16 * 72];     // f32 (V-K)[i][d]
  __shared__ __align__(16) short sX2b[16 * 264];   // bf16 X2[i][p]
  __shared__ __align__(16) short sXbb[16 * 264];   // bf16 X2_bar[i][p]
  __shared__ __align__(16) short sG1c[256 * 24];   // bf16 gZ1 col-major [p][j]
  __shared__ __align__(16) short sG2b[16 * 72];    // bf16 gZ2[i][d]
  __shared__ __align__(16) short sG2c[64 * 24];    // bf16 gZ2 col-major [d][j]
  __shared__ __align__(16) float sZ2f[16 * 68];    // f32 Z2 / Z2_bar
  __shared__ __align__(16) short sC1b[16 * 24];    // bf16 C1'[i][j]
  __shared__ __align__(16) short sC2b[16 * 24];    // bf16 C2'[i][j]
  __shared__ __align__(16) float sB1[256];
  __shared__ __align__(16) float sB2[64];
  __shared__ float sLr[16];
  __shared__ float sTok[16];
  __shared__ __align__(16) float sLnw[64];
  __shared__ __align__(16) float sLnb[64];

  const int bh = blockIdx.x, b = bh >> 4, h = bh & 15;
  const int tid = threadIdx.x;
  const int w = tid >> 6, ln = tid & 63;
  const int fr = ln & 15, half = ln >> 4, hk = half * 8;
  const int nt0 = 2 * w;

  // ---- fp32 masters in registers.
  // W1 tile T=w*8+r: dt=T>>4, pt=T&15 -> w1m[r][qq] = W1[p=pt*16+fr][d=dt*16+half*4+qq]
  // W2 tile T=w*8+r: pt=T&15, dt=T>>4 -> w2m[r][qq] = W2[p=pt*16+half*4+qq][d=dt*16+fr]
  float w1m[8][4], w2m[8][4];
#pragma unroll
  for (int r = 0; r < 8; ++r) {
    const int T = w * 8 + r, dt = T >> 4, pt = T & 15;
#pragma unroll
    for (int qq = 0; qq < 4; ++qq) {
      w1m[r][qq] = W1in[h * 16384 + (dt * 16 + half * 4 + qq) * 256 + pt * 16 + fr];
      w2m[r][qq] = W2in[h * 16384 + (pt * 16 + half * 4 + qq) * 64 + dt * 16 + fr];
    }
  }
  // bf16 LDS copies
  for (int e = tid; e < 16384; e += 512) {
    {  // W1in layout [d=64][p=256]
      const int d = e >> 8, p = e & 255;
      sW1b[p * 72 + d] = f2bf(W1in[h * 16384 + e]);
    }
    {  // W2in layout [p=256][d=64]
      const int p = e >> 6, d = e & 63;
      sW2dp[d * 264 + (p ^ (((d >> 3) & 3) << 3))] = f2bf(W2in[h * 16384 + e]);
    }
  }
  if (tid < 256) sB1[tid] = b1in[h * 256 + tid];
  if (tid < 64) { sB2[tid] = b2in[h * 64 + tid]; sLnw[tid] = nw[h * 64 + tid]; sLnb[tid] = nb[h * 64 + tid]; }
  if (tid < 16) sTok[tid] = fmaxf(1.0f / (float)(tid + 1) + lti[tid], 0.0f);

  const f32x4 zf4 = (f32x4){0.f, 0.f, 0.f, 0.f};
  short8 zs8;
#pragma unroll
  for (int j = 0; j < 8; ++j) zs8[j] = 0;

  // chunk-input prefetch (regs)
  const int pf_i = tid >> 5;
  const int pf_d = (tid & 31) * 2;
  f32x2 pk, pq, pv;
  float plr = 0.f;
  {
    const long a0 = ((long)(b * LLL + pf_i)) * WIDTH + h * 64 + pf_d;
    pk = *(const f32x2*)&Kb[a0];
    pq = *(const f32x2*)&Qb[a0];
    pv = *(const f32x2*)&Vb[a0];
    if (tid < 16) plr = LRb[(long)bh * 2048 + tid];
  }

  for (int n = 0; n < NCHUNK; ++n) {
    const long gbase = ((long)(b * LLL + n * MBSZ)) * WIDTH + h * 64;

    // ---- commit prefetched chunk to LDS
    {
      const unsigned uk = ((unsigned)(unsigned short)f2bf(pk[0])) | (((unsigned)(unsigned short)f2bf(pk[1])) << 16);
      const unsigned uq = ((unsigned)(unsigned short)f2bf(pq[0])) | (((unsigned)(unsigned short)f2bf(pq[1])) << 16);
      *(unsigned*)&sX1b[pf_i * 72 + pf_d] = uk;
      *(unsigned*)&sXQb[pf_i * 72 + pf_d] = uq;
      sTg[pf_i * 72 + pf_d] = pv[0] - pk[0];
      sTg[pf_i * 72 + pf_d + 1] = pv[1] - pk[1];
      if (tid < 16) sLr[tid] = plr;
    }
    __syncthreads();  // A

    // ---- B: Z1 & XQ@W1 (MFMA) -> z1/q1; X2->LDS; la1T; C1 (wave 0)
    short8 aX1[2], aXQ[2];
    aX1[0] = *(const short8*)&sX1b[fr * 72 + hk];
    aX1[1] = *(const short8*)&sX1b[fr * 72 + 32 + hk];
    aXQ[0] = *(const short8*)&sXQb[fr * 72 + hk];
    aXQ[1] = *(const short8*)&sXQb[fr * 72 + 32 + hk];
    f32x4 z1[2], q1[2];
    float b1p[2];
#pragma unroll
    for (int t = 0; t < 2; ++t) {
      const int p = (nt0 + t) * 16 + fr;
      z1[t] = zf4; q1[t] = zf4;
#pragma unroll
      for (int ks = 0; ks < 2; ++ks) {
        short8 bw = *(const short8*)&sW1b[p * 72 + ks * 32 + hk];
        z1[t] = MFMA16(aX1[ks], bw, z1[t]);
        q1[t] = MFMA16(aXQ[ks], bw, q1[t]);
      }
      b1p[t] = sB1[p];
#pragma unroll
      for (int qq = 0; qq < 4; ++qq) {
        z1[t][qq] += b1p[t];
        sX2b[(half * 4 + qq) * 264 + p] = f2bf(gelu_f(z1[t][qq]));
      }
    }
    {
      const float tok15 = sTok[15];
#pragma unroll
      for (int k = 0; k < 2; ++k) {
        const int e = tid + k * 512, d = e >> 4, j = e & 15;
        la1T[d * 24 + j] = f2bf(bf2f(sX1b[j * 72 + d]) * (tok15 * sLr[j]));
      }
    }
    if (w == 0) {
      f32x4 c = MFMA16(aXQ[0], aX1[0], zf4);
      c = MFMA16(aXQ[1], aX1[1], c);
#pragma unroll
      for (int qq = 0; qq < 4; ++qq) {
        const int i = half * 4 + qq, j = fr;
        sC1b[i * 24 + j] = f2bf((i >= j) ? sTok[i] * sLr[j] * (c[qq] + 1.0f) : 0.0f);
      }
    }
    __syncthreads();  // B

    // ---- C: Z2 = X2@W2 + b2 (waves 0-3) | la2T (waves 4-7)
    float bb2old = 0.f;
    if (w < 4) {
      const int d = w * 16 + fr;
      const int sw = ((d >> 3) & 3) << 3;
      f32x4 za = zf4, zb = zf4;
#pragma unroll
      for (int ks = 0; ks < 4; ++ks) {
        short8 a = *(const short8*)&sX2b[fr * 264 + ks * 32 + hk];
        short8 bfr = *(const short8*)&sW2dp[d * 264 + ((ks * 32 + hk) ^ sw)];
        za = MFMA16(a, bfr, za);
      }
#pragma unroll
      for (int ks = 4; ks < 8; ++ks) {
        short8 a = *(const short8*)&sX2b[fr * 264 + ks * 32 + hk];
        short8 bfr = *(const short8*)&sW2dp[d * 264 + ((ks * 32 + hk) ^ sw)];
        zb = MFMA16(a, bfr, zb);
      }
      bb2old = sB2[d];
#pragma unroll
      for (int qq = 0; qq < 4; ++qq)
        sZ2f[(half * 4 + qq) * 68 + d] = za[qq] + zb[qq] + bb2old;
    } else {
      const int t0 = tid - 256;
      const float tok15 = sTok[15];
#pragma unroll
      for (int k = 0; k < 16; ++k) {
        const int e = t0 + k * 256, pp = e >> 4, j = e & 15;
        la2T[pp * 24 + j] = f2bf(bf2f(sX2b[j * 264 + pp]) * (tok15 * sLr[j]));
      }
    }
    __syncthreads();  // C

    // ---- D: gZ2 = ln_l2_bwd(Z2, V-K)  (tid<256)
    if (tid < 256) {
      const int i = tid >> 4, j4 = tid & 15;
      const f32x4 z = *(const f32x4*)&sZ2f[i * 68 + j4 * 4];
      float s1 = z[0] + z[1] + z[2] + z[3];
      float s2 = z[0] * z[0] + z[1] * z[1] + z[2] * z[2] + z[3] * z[3];
#pragma unroll
      for (int o = 8; o; o >>= 1) { s1 += __shfl_xor(s1, o, 16); s2 += __shfl_xor(s2, o, 16); }
      const float mu = s1 * (1.f / 64.f);
      const float rstd = rsqrtf(s2 * (1.f / 64.f) - mu * mu + 1e-6f);
      const f32x4 g = *(const f32x4*)&sLnw[j4 * 4];
      const f32x4 bb = *(const f32x4*)&sLnb[j4 * 4];
      const f32x4 tg = *(const f32x4*)&sTg[i * 72 + j4 * 4];
      f32x4 xh, gx;
      float a1 = 0.f, a2 = 0.f;
#pragma unroll
      for (int e = 0; e < 4; ++e) {
        xh[e] = (z[e] - mu) * rstd;
        gx[e] = (g[e] * xh[e] + bb[e] - tg[e]) * g[e];
        a1 += gx[e]; a2 += gx[e] * xh[e];
      }
#pragma unroll
      for (int o = 8; o; o >>= 1) { a1 += __shfl_xor(a1, o, 16); a2 += __shfl_xor(a2, o, 16); }
      const float m1 = a1 * (1.f / 64.f), m2 = a2 * (1.f / 64.f);
#pragma unroll
      for (int e = 0; e < 4; ++e) {
        const int d = j4 * 4 + e;
        const short v = f2bf((gx[e] - m1 - xh[e] * m2) * rstd);
        sG2b[i * 72 + d] = v;
        sG2c[d * 24 + i] = v;
      }
    }
    __syncthreads();  // D

    // ---- E: gZ1 = (gZ2@W2^T)*gelu_bwd(Z1) -> sG1c (all waves) | b2 update (tid<64)
    {
      short8 aG2[2];
      aG2[0] = *(const short8*)&sG2b[fr * 72 + hk];
      aG2[1] = *(const short8*)&sG2b[fr * 72 + 32 + hk];
#pragma unroll
      for (int t = 0; t < 2; ++t) {
        const int p = (nt0 + t) * 16 + fr;
        f32x4 g = zf4;
#pragma unroll
        for (int ks = 0; ks < 2; ++ks) {
          short8 bw;
#pragma unroll
          for (int jj = 0; jj < 8; ++jj) {
            const int d = ks * 32 + hk + jj;
            bw[jj] = sW2dp[d * 264 + (p ^ (((d >> 3) & 3) << 3))];
          }
          g = MFMA16(aG2[ks], bw, g);
        }
#pragma unroll
        for (int qq = 0; qq < 4; ++qq)
          sG1c[p * 24 + half * 4 + qq] = f2bf(g[qq] * gelu_bwd_f(z1[t][qq]));
      }
    }
    if (tid < 64) {
      float s = 0.f;
#pragma unroll
      for (int j = 0; j < 16; ++j) s += sLr[j] * bf2f(sG2c[tid * 24 + j]);
      sB2[tid] -= sTok[15] * s;
    }
    __syncthreads();  // E

    // ---- F: X2_bar (all) | W1 reg-update (all) | b1 update (tid<256)
    {
      short8 ac = zs8;
      if (half < 2) ac = *(const short8*)&sC1b[fr * 24 + hk];
#pragma unroll
      for (int t = 0; t < 2; ++t) {
        const int p = (nt0 + t) * 16 + fr;
        short8 bg = zs8;
        if (half < 2) bg = *(const short8*)&sG1c[p * 24 + hk];
        f32x4 corr = MFMA16(ac, bg, zf4);
#pragma unroll
        for (int qq = 0; qq < 4; ++qq)
          sXbb[(half * 4 + qq) * 264 + p] = f2bf(gelu_f(q1[t][qq] + b1p[t] - corr[qq]));
      }
    }
    {
#pragma unroll
      for (int r = 0; r < 8; ++r) {
        const int T = w * 8 + r, dt = T >> 4, pt = T & 15;
        short8 af = zs8, bg = zs8;
        if (half < 2) {
          af = *(const short8*)&la1T[(dt * 16 + fr) * 24 + hk];
          bg = *(const short8*)&sG1c[(pt * 16 + fr) * 24 + hk];
        }
        f32x4 dl = MFMA16(af, bg, zf4);
        const int pp = pt * 16 + fr, d0 = dt * 16 + half * 4;
#pragma unroll
        for (int qq = 0; qq < 4; ++qq) {
          w1m[r][qq] -= dl[qq];
          sW1b[pp * 72 + d0 + qq] = f2bf(w1m[r][qq]);
        }
      }
    }
    if (tid < 256) {
      float s = 0.f;
#pragma unroll
      for (int j = 0; j < 16; ++j) s += sLr[j] * bf2f(sG1c[tid * 24 + j]);
      sB1[tid] -= sTok[15] * s;
    }
    __syncthreads();  // F

    // ---- G: prefetch issue; Z2bar partial (w0-3) | C2 (w4)
    {
      const int nn = (n + 1 < NCHUNK) ? n + 1 : n;
      const long a1 = ((long)(b * LLL + nn * MBSZ + pf_i)) * WIDTH + h * 64 + pf_d;
      pk = *(const f32x2*)&Kb[a1];
      pq = *(const f32x2*)&Qb[a1];
      pv = *(const f32x2*)&Vb[a1];
      if (tid < 16) plr = LRb[(long)bh * 2048 + nn * MBSZ + tid];
    }
    f32x4 zbar = zf4;
    if (w < 4) {
      const int d = w * 16 + fr;
      const int sw = ((d >> 3) & 3) << 3;
      f32x4 za = zf4, zb = zf4;
#pragma unroll
      for (int ks = 0; ks < 4; ++ks) {
        short8 a = *(const short8*)&sXbb[fr * 264 + ks * 32 + hk];
        short8 bfr = *(const short8*)&sW2dp[d * 264 + ((ks * 32 + hk) ^ sw)];
        za = MFMA16(a, bfr, za);
      }
#pragma unroll
      for (int ks = 4; ks < 8; ++ks) {
        short8 a = *(const short8*)&sXbb[fr * 264 + ks * 32 + hk];
        short8 bfr = *(const short8*)&sW2dp[d * 264 + ((ks * 32 + hk) ^ sw)];
        zb = MFMA16(a, bfr, zb);
      }
      zbar[0] = za[0] + zb[0]; zbar[1] = za[1] + zb[1];
      zbar[2] = za[2] + zb[2]; zbar[3] = za[3] + zb[3];
    } else if (w == 4) {
      f32x4 c = zf4;
#pragma unroll
      for (int ks = 0; ks < 8; ++ks) {
        short8 a = *(const short8*)&sXbb[fr * 264 + ks * 32 + hk];
        short8 bx = *(const short8*)&sX2b[fr * 264 + ks * 32 + hk];
        c = MFMA16(a, bx, c);
      }
#pragma unroll
      for (int qq = 0; qq < 4; ++qq) {
        const int i = half * 4 + qq, j = fr;
        sC2b[i * 24 + j] = f2bf((i >= j) ? sTok[i] * sLr[j] * (c[qq] + 1.0f) : 0.0f);
      }
    }
    __syncthreads();  // G

    // ---- H: Z2bar finalize (w0-3) + W2 reg-update (ALL waves, 8 tiles each)
    if (w < 4) {
      const int d = w * 16 + fr;
      short8 ac = zs8, bg = zs8;
      if (half < 2) {
        ac = *(const short8*)&sC2b[fr * 24 + hk];
        bg = *(const short8*)&sG2c[d * 24 + hk];
      }
      f32x4 corr = MFMA16(ac, bg, zf4);
#pragma unroll
      for (int qq = 0; qq < 4; ++qq)
        sZ2f[(half * 4 + qq) * 68 + d] = zbar[qq] + bb2old - corr[qq];
    }
    {
#pragma unroll
      for (int r = 0; r < 8; ++r) {
        const int T = w * 8 + r, pt = T & 15, dt = T >> 4;
        short8 af = zs8, bg = zs8;
        if (half < 2) {
          af = *(const short8*)&la2T[(pt * 16 + fr) * 24 + hk];
          bg = *(const short8*)&sG2c[(dt * 16 + fr) * 24 + hk];
        }
        f32x4 dl = MFMA16(af, bg, zf4);
        const int dd = dt * 16 + fr;
        const int swp = ((dd >> 3) & 3) << 3;
        const int p0 = pt * 16 + half * 4;
#pragma unroll
        for (int qq = 0; qq < 4; ++qq) {
          w2m[r][qq] -= dl[qq];
          sW2dp[dd * 264 + ((p0 + qq) ^ swp)] = f2bf(w2m[r][qq]);
        }
      }
    }
    __syncthreads();  // H

    // ---- I: XQW = XQ + ln_fwd(Z2_bar) -> Qb  (tid<256)
    if (tid < 256) {
      const int i = tid >> 4, j4 = tid & 15;
      const f32x4 z = *(const f32x4*)&sZ2f[i * 68 + j4 * 4];
      float s1 = z[0] + z[1] + z[2] + z[3];
      float s2 = z[0] * z[0] + z[1] * z[1] + z[2] * z[2] + z[3] * z[3];
#pragma unroll
      for (int o = 8; o; o >>= 1) { s1 += __shfl_xor(s1, o, 16); s2 += __shfl_xor(s2, o, 16); }
      const float mu = s1 * (1.f / 64.f);
      const float rstd = rsqrtf(s2 * (1.f / 64.f) - mu * mu + 1e-6f);
      const f32x4 g = *(const f32x4*)&sLnw[j4 * 4];
      const f32x4 bb = *(const f32x4*)&sLnb[j4 * 4];
      f32x4 xq = *(const f32x4*)&Qb[gbase + (long)i * WIDTH + j4 * 4];
      f32x4 o4;
#pragma unroll
      for (int e = 0; e < 4; ++e) o4[e] = xq[e] + g[e] * ((z[e] - mu) * rstd) + bb[e];
      *(f32x4*)&Qb[gbase + (long)i * WIDTH + j4 * 4] = o4;
    }
    __syncthreads();  // I (protects shared buffers for next chunk)
  }
}

// ---------------- epilogue: tmp = gelu(G) * ln_fwd(XQW, post_w, post_b)
__global__ __launch_bounds__(256) void epi_kernel(const float* __restrict__ X,
                                                  const float* __restrict__ G,
                                                  const float* __restrict__ pw,
                                                  const float* __restrict__ pb,
                                                  float* __restrict__ T) {
  __shared__ float red[8];
  const int t = blockIdx.x, tid = threadIdx.x;
  const long base = (long)t * 1024 + tid * 4;
  f32x4 x = *(const f32x4*)&X[base];
  float s1 = x[0] + x[1] + x[2] + x[3];
  float s2 = x[0] * x[0] + x[1] * x[1] + x[2] * x[2] + x[3] * x[3];
#pragma unroll
  for (int o = 32; o; o >>= 1) { s1 += __shfl_xor(s1, o, 64); s2 += __shfl_xor(s2, o, 64); }
  const int wv = tid >> 6, ln = tid & 63;
  if (ln == 0) { red[wv] = s1; red[4 + wv] = s2; }
  __syncthreads();
  s1 = red[0] + red[1] + red[2] + red[3];
  s2 = red[4] + red[5] + red[6] + red[7];
  const float mu = s1 * (1.f / 1024.f);
  const float rstd = rsqrtf(s2 * (1.f / 1024.f) - mu * mu + 1e-6f);
  f32x4 g = *(const f32x4*)&G[base];
  f32x4 w = *(const f32x4*)&pw[tid * 4];
  f32x4 bb = *(const f32x4*)&pb[tid * 4];
  f32x4 o4;
#pragma unroll
  for (int e = 0; e < 4; ++e) {
    float y = w[e] * ((x[e] - mu) * rstd) + bb[e];
    o4[e] = gelu_f(g[e]) * y;
  }
  *(f32x4*)&T[base] = o4;
}

extern "C" void kernel_launch(void* const* d_in, const int* in_sizes, int n_in,
                              void* d_out, int out_size, void* d_ws, size_t ws_size,
                              hipStream_t stream) {
  const float* hs  = (const float*)d_in[0];
  const float* Wq  = (const float*)d_in[1];
  const float* Wk  = (const float*)d_in[2];
  const float* Wv  = (const float*)d_in[3];
  const float* Wo  = (const float*)d_in[4];
  const float* Wg  = (const float*)d_in[5];
  const float* lrw = (const float*)d_in[6];
  const float* lrb = (const float*)d_in[7];
  const float* lti = (const float*)d_in[8];
  const float* nw  = (const float*)d_in[9];
  const float* nb  = (const float*)d_in[10];
  const float* W1  = (const float*)d_in[11];
  const float* b1  = (const float*)d_in[12];
  const float* W2  = (const float*)d_in[13];
  const float* b2  = (const float*)d_in[14];
  const float* pw  = (const float*)d_in[15];
  const float* pb  = (const float*)d_in[16];
  float* out = (float*)d_out;
  float* ws = (float*)d_ws;

  float* Qb  = ws;
  float* Kb  = ws + 8388608;
  float* Vb  = ws + 16777216;
  float* Gb  = ws + 25165824;
  float* LRb = ws + 33554432;

  dim3 gg(128, 16);
  gemm_bt<<<gg, 256, 0, stream>>>(hs, Wq, Qb);
  gemm_bt<<<gg, 256, 0, stream>>>(hs, Wk, Kb);
  gemm_bt<<<gg, 256, 0, stream>>>(hs, Wv, Vb);
  gemm_bt<<<gg, 256, 0, stream>>>(hs, Wg, Gb);
  lr_kernel<<<8192, 256, 0, stream>>>(hs, lrw, lrb, LRb);
  scan_kernel<<<64, 512, 0, stream>>>(Qb, Kb, Vb, LRb, lti, nw, nb, W1, b1, W2, b2);
  epi_kernel<<<8192, 256, 0, stream>>>(Qb, Gb, pw, pb, Kb);
  gemm_bt<<<gg, 256, 0, stream>>>(Kb, Wo, out);
}

// Round 6
// 1054.173 us; speedup vs baseline: 42.4758x; 1.2339x over previous
//
#include <hip/hip_runtime.h>

#define WIDTH 1024
#define MBSZ 16
#define LLL 2048
#define NCHUNK 128

typedef __attribute__((ext_vector_type(4))) float f32x4;
typedef __attribute__((ext_vector_type(2))) float f32x2;
typedef __attribute__((ext_vector_type(8))) short short8;
typedef __attribute__((ext_vector_type(2))) unsigned u32x2;
typedef __attribute__((ext_vector_type(4))) unsigned u32x4;

#define MFMA16(a, b, c) __builtin_amdgcn_mfma_f32_16x16x32_bf16((a), (b), (c), 0, 0, 0)

__device__ __forceinline__ short f2bf(float f) {
  unsigned u = __float_as_uint(f);
  u = (u + 0x7FFFu + ((u >> 16) & 1u)) >> 16;  // RNE f32->bf16
  return (short)u;
}
__device__ __forceinline__ float bf2f(short s) {
  return __uint_as_float(((unsigned)(unsigned short)s) << 16);
}
// packed RNE f32x2 -> bf16x2 (single VALU inst)
__device__ __forceinline__ unsigned cvt_pk(float lo, float hi) {
  unsigned r;
  asm("v_cvt_pk_bf16_f32 %0, %1, %2" : "=v"(r) : "v"(lo), "v"(hi));
  return r;
}
// e^{2u(x)} with u = 0.79788456 x (1 + 0.044715 x^2)
__device__ __forceinline__ float fast_e2u(float x) {
  return __builtin_amdgcn_exp2f(x * (2.30220776f + 0.10294322f * x * x));
}
__device__ __forceinline__ float gelu_f(float x) {
  float e = fast_e2u(x);
  return x * (1.0f - __builtin_amdgcn_rcpf(e + 1.0f));
}
__device__ __forceinline__ float gelu_bwd_f(float x) {
  float e = fast_e2u(x);
  float r = __builtin_amdgcn_rcpf(e + 1.0f);
  return 2.0f * x * r * (1.0f - r) * (0.79788456f + 0.1070322243f * x * x) + (1.0f - r);
}
// sW2dp row base (shorts): +24-short pad per 8-row group breaks the 8-row bank alignment
__device__ __forceinline__ int w2row(int d) { return d * 264 + (d >> 3) * 24; }

// ---------------- C[8192][1024] = A[8192][1024] @ W[1024][1024]^T (bf16 MFMA, fp32 in/out)
__global__ __launch_bounds__(256) void gemm_bt(const float* __restrict__ A,
                                               const float* __restrict__ W,
                                               float* __restrict__ C) {
  __shared__ __align__(16) short sA[64][40];
  __shared__ __align__(16) short sB[64][40];
  const int tid = threadIdx.x;
  const int m0 = blockIdx.x * 64, n0 = blockIdx.y * 64;
  const int srow = tid >> 2, sk = (tid & 3) * 8;
  const int wv = tid >> 6, ln = tid & 63;
  const int fr = ln & 15, kh = (ln >> 4) * 8;
  f32x4 acc[4];
#pragma unroll
  for (int s = 0; s < 4; ++s) acc[s] = (f32x4){0.f, 0.f, 0.f, 0.f};
  const float* ga = A + (long)(m0 + srow) * 1024 + sk;
  const float* gw = W + (long)(n0 + srow) * 1024 + sk;
  for (int k0 = 0; k0 < 1024; k0 += 32) {
    f32x4 a0 = *(const f32x4*)(ga + k0);
    f32x4 a1 = *(const f32x4*)(ga + k0 + 4);
    f32x4 w0 = *(const f32x4*)(gw + k0);
    f32x4 w1 = *(const f32x4*)(gw + k0 + 4);
    short8 pa, pw;
    pa[0] = f2bf(a0[0]); pa[1] = f2bf(a0[1]); pa[2] = f2bf(a0[2]); pa[3] = f2bf(a0[3]);
    pa[4] = f2bf(a1[0]); pa[5] = f2bf(a1[1]); pa[6] = f2bf(a1[2]); pa[7] = f2bf(a1[3]);
    pw[0] = f2bf(w0[0]); pw[1] = f2bf(w0[1]); pw[2] = f2bf(w0[2]); pw[3] = f2bf(w0[3]);
    pw[4] = f2bf(w1[0]); pw[5] = f2bf(w1[1]); pw[6] = f2bf(w1[2]); pw[7] = f2bf(w1[3]);
    *(short8*)&sA[srow][sk] = pa;
    *(short8*)&sB[srow][sk] = pw;
    __syncthreads();
    short8 af = *(const short8*)&sA[wv * 16 + fr][kh];
#pragma unroll
    for (int s = 0; s < 4; ++s) {
      short8 bf8 = *(const short8*)&sB[s * 16 + fr][kh];
      acc[s] = MFMA16(af, bf8, acc[s]);
    }
    __syncthreads();
  }
  const int orow = m0 + wv * 16 + (ln >> 4) * 4;
#pragma unroll
  for (int s = 0; s < 4; ++s)
#pragma unroll
    for (int q = 0; q < 4; ++q)
      C[(long)(orow + q) * 1024 + n0 + s * 16 + fr] = acc[s][q];
}

// ---------------- lr_eta[b,h,t] = sigmoid(hs[t]·lr_w[h] + lr_b[h]) / 64
__global__ __launch_bounds__(256) void lr_kernel(const float* __restrict__ hs,
                                                 const float* __restrict__ lrw,
                                                 const float* __restrict__ lrb,
                                                 float* __restrict__ out) {
  __shared__ __align__(16) float row[1024];
  const int t = blockIdx.x, tid = threadIdx.x;
  *(f32x4*)&row[tid * 4] = *(const f32x4*)&hs[(long)t * 1024 + tid * 4];
  __syncthreads();
  const int hh = tid >> 4, j = tid & 15;
  const float* wrow = lrw + hh * 1024;
  float s = 0.f;
#pragma unroll 4
  for (int m = 0; m < 16; ++m) {
    const int c = j * 4 + m * 64;
    f32x4 x = *(const f32x4*)&row[c];
    f32x4 w = *(const f32x4*)&wrow[c];
    s += x[0] * w[0] + x[1] * w[1] + x[2] * w[2] + x[3] * w[3];
  }
#pragma unroll
  for (int o = 8; o; o >>= 1) s += __shfl_xor(s, o, 16);
  if (j == 0) {
    const float v = s + lrb[hh];
    const float sg = 1.f / (1.f + expf(-v));
    const int b = t >> 11, tr = t & 2047;
    out[((b << 4) + hh) * 2048 + tr] = sg * (1.f / 64.f);
  }
}

// ---------------- sequential TTT scan: one block of 512 per (b,h)
__global__ __launch_bounds__(512, 2) void scan_kernel(
    float* __restrict__ Qb, const float* __restrict__ Kb, const float* __restrict__ Vb,
    const float* __restrict__ LRb, const float* __restrict__ lti,
    const float* __restrict__ nw, const float* __restrict__ nb,
    const float* __restrict__ W1in, const float* __restrict__ b1in,
    const float* __restrict__ W2in, const float* __restrict__ b2in) {
  __shared__ __align__(16) short sW1b[256 * 72];        // bf16 W1[p][d]
  __shared__ __align__(16) short sW2dp[64 * 264 + 192]; // bf16 W2[d][p^sw], group-padded rows
  __shared__ __align__(16) short la1T[64 * 24];
  __shared__ __align__(16) short la2T[256 * 24];
  __shared__ __align__(16) short sX1b[16 * 72];
  __shared__ __align__(16) short sXQb[16 * 72];
  __shared__ __align__(16) float sXQf[16 * 68];         // fp32 XQ (for phase I)
  __shared__ __align__(16) float sTg[16 * 72];
  __shared__ __align__(16) short sX2b[16 * 264];
  __shared__ __align__(16) short sXbb[16 * 264];
  __shared__ __align__(16) short sG1c[256 * 24];
  __shared__ __align__(16) short sG2b[16 * 72];
  __shared__ __align__(16) short sG2c[64 * 24];
  __shared__ __align__(16) float sZ2f[16 * 68];
  __shared__ __align__(16) short sC1b[16 * 24];
  __shared__ __align__(16) short sC2b[16 * 24];
  __shared__ __align__(16) float sB1[256];
  __shared__ __align__(16) float sB2[64];
  __shared__ float sLr[16];
  __shared__ float sTok[16];
  __shared__ __align__(16) float sLnw[64];
  __shared__ __align__(16) float sLnb[64];

  const int bh = blockIdx.x, b = bh >> 4, h = bh & 15;
  const int tid = threadIdx.x;
  const int w = tid >> 6, ln = tid & 63;
  const int fr = ln & 15, half = ln >> 4, hk = half * 8;
  const int nt0 = 2 * w;

  // fp32 masters in registers (stationary fragment ownership)
  float w1m[8][4], w2m[8][4];
#pragma unroll
  for (int r = 0; r < 8; ++r) {
    const int T = w * 8 + r, dt = T >> 4, pt = T & 15;
#pragma unroll
    for (int qq = 0; qq < 4; ++qq) {
      w1m[r][qq] = W1in[h * 16384 + (dt * 16 + half * 4 + qq) * 256 + pt * 16 + fr];
      w2m[r][qq] = W2in[h * 16384 + (pt * 16 + half * 4 + qq) * 64 + dt * 16 + fr];
    }
  }
  for (int e = tid; e < 16384; e += 512) {
    {  // W1in [d][p]
      const int d = e >> 8, p = e & 255;
      sW1b[p * 72 + d] = f2bf(W1in[h * 16384 + e]);
    }
    {  // W2in [p][d]
      const int p = e >> 6, d = e & 63;
      sW2dp[w2row(d) + (p ^ (((d >> 3) & 3) << 3))] = f2bf(W2in[h * 16384 + e]);
    }
  }
  if (tid < 256) sB1[tid] = b1in[h * 256 + tid];
  if (tid < 64) { sB2[tid] = b2in[h * 64 + tid]; sLnw[tid] = nw[h * 64 + tid]; sLnb[tid] = nb[h * 64 + tid]; }
  if (tid < 16) sTok[tid] = fmaxf(1.0f / (float)(tid + 1) + lti[tid], 0.0f);

  const f32x4 zf4 = (f32x4){0.f, 0.f, 0.f, 0.f};
  short8 zs8;
#pragma unroll
  for (int j = 0; j < 8; ++j) zs8[j] = 0;

  // chunk-input prefetch (regs)
  const int pf_i = tid >> 5;
  const int pf_d = (tid & 31) * 2;
  f32x2 pk, pq, pv;
  float plr = 0.f;
  {
    const long a0 = ((long)(b * LLL + pf_i)) * WIDTH + h * 64 + pf_d;
    pk = *(const f32x2*)&Kb[a0];
    pq = *(const f32x2*)&Qb[a0];
    pv = *(const f32x2*)&Vb[a0];
    if (tid < 16) plr = LRb[(long)bh * 2048 + tid];
  }

  for (int n = 0; n < NCHUNK; ++n) {
    const long gbase = ((long)(b * LLL + n * MBSZ)) * WIDTH + h * 64;

    // ---- commit prefetched chunk to LDS
    {
      *(unsigned*)&sX1b[pf_i * 72 + pf_d] = cvt_pk(pk[0], pk[1]);
      *(unsigned*)&sXQb[pf_i * 72 + pf_d] = cvt_pk(pq[0], pq[1]);
      sXQf[pf_i * 68 + pf_d] = pq[0];
      sXQf[pf_i * 68 + pf_d + 1] = pq[1];
      sTg[pf_i * 72 + pf_d] = pv[0] - pk[0];
      sTg[pf_i * 72 + pf_d + 1] = pv[1] - pk[1];
      if (tid < 16) sLr[tid] = plr;
    }
    __syncthreads();  // A

    // ---- B: Z1 & XQ@W1 -> z1/q1; X2->LDS; la1T; C1 (wave 0)
    short8 aX1[2], aXQ[2];
    aX1[0] = *(const short8*)&sX1b[fr * 72 + hk];
    aX1[1] = *(const short8*)&sX1b[fr * 72 + 32 + hk];
    aXQ[0] = *(const short8*)&sXQb[fr * 72 + hk];
    aXQ[1] = *(const short8*)&sXQb[fr * 72 + 32 + hk];
    f32x4 z1[2], q1[2];
    float b1p[2];
#pragma unroll
    for (int t = 0; t < 2; ++t) {
      const int p = (nt0 + t) * 16 + fr;
      z1[t] = zf4; q1[t] = zf4;
#pragma unroll
      for (int ks = 0; ks < 2; ++ks) {
        short8 bw = *(const short8*)&sW1b[p * 72 + ks * 32 + hk];
        z1[t] = MFMA16(aX1[ks], bw, z1[t]);
        q1[t] = MFMA16(aXQ[ks], bw, q1[t]);
      }
      b1p[t] = sB1[p];
#pragma unroll
      for (int qq = 0; qq < 4; ++qq) {
        z1[t][qq] += b1p[t];
        sX2b[(half * 4 + qq) * 264 + p] = f2bf(gelu_f(z1[t][qq]));
      }
    }
    {  // la1T: thread -> (row d=tid>>3, j pair)
      const float tok15 = sTok[15];
      const int d = tid >> 3, j0 = (tid & 7) * 2;
      const float v0 = bf2f(sX1b[j0 * 72 + d]) * (tok15 * sLr[j0]);
      const float v1 = bf2f(sX1b[(j0 + 1) * 72 + d]) * (tok15 * sLr[j0 + 1]);
      *(unsigned*)&la1T[d * 24 + j0] = cvt_pk(v0, v1);
    }
    if (w == 0) {
      f32x4 c = MFMA16(aXQ[0], aX1[0], zf4);
      c = MFMA16(aXQ[1], aX1[1], c);
#pragma unroll
      for (int qq = 0; qq < 4; ++qq) {
        const int i = half * 4 + qq, j = fr;
        sC1b[i * 24 + j] = f2bf((i >= j) ? sTok[i] * sLr[j] * (c[qq] + 1.0f) : 0.0f);
      }
    }
    __syncthreads();  // B

    // ---- C: Z2 = X2@W2 + b2 (waves 0-3)
    float bb2old = 0.f;
    if (w < 4) {
      const int d = w * 16 + fr;
      const int sw = ((d >> 3) & 3) << 3;
      const int rb = w2row(d);
      f32x4 za = zf4, zb = zf4;
#pragma unroll
      for (int ks = 0; ks < 4; ++ks) {
        short8 a = *(const short8*)&sX2b[fr * 264 + ks * 32 + hk];
        short8 bfr = *(const short8*)&sW2dp[rb + ((ks * 32 + hk) ^ sw)];
        za = MFMA16(a, bfr, za);
      }
#pragma unroll
      for (int ks = 4; ks < 8; ++ks) {
        short8 a = *(const short8*)&sX2b[fr * 264 + ks * 32 + hk];
        short8 bfr = *(const short8*)&sW2dp[rb + ((ks * 32 + hk) ^ sw)];
        zb = MFMA16(a, bfr, zb);
      }
      bb2old = sB2[d];
#pragma unroll
      for (int qq = 0; qq < 4; ++qq)
        sZ2f[(half * 4 + qq) * 68 + d] = za[qq] + zb[qq] + bb2old;
    }
    __syncthreads();  // C

    // ---- D: gZ2 = ln_l2_bwd (tid<256) | la2T build (tid>=256)
    if (tid < 256) {
      const int i = tid >> 4, j4 = tid & 15;
      const f32x4 z = *(const f32x4*)&sZ2f[i * 68 + j4 * 4];
      float s1 = z[0] + z[1] + z[2] + z[3];
      float s2 = z[0] * z[0] + z[1] * z[1] + z[2] * z[2] + z[3] * z[3];
#pragma unroll
      for (int o = 8; o; o >>= 1) { s1 += __shfl_xor(s1, o, 16); s2 += __shfl_xor(s2, o, 16); }
      const float mu = s1 * (1.f / 64.f);
      const float rstd = rsqrtf(s2 * (1.f / 64.f) - mu * mu + 1e-6f);
      const f32x4 g = *(const f32x4*)&sLnw[j4 * 4];
      const f32x4 bb = *(const f32x4*)&sLnb[j4 * 4];
      const f32x4 tg = *(const f32x4*)&sTg[i * 72 + j4 * 4];
      f32x4 xh, gx;
      float a1 = 0.f, a2 = 0.f;
#pragma unroll
      for (int e = 0; e < 4; ++e) {
        xh[e] = (z[e] - mu) * rstd;
        gx[e] = (g[e] * xh[e] + bb[e] - tg[e]) * g[e];
        a1 += gx[e]; a2 += gx[e] * xh[e];
      }
#pragma unroll
      for (int o = 8; o; o >>= 1) { a1 += __shfl_xor(a1, o, 16); a2 += __shfl_xor(a2, o, 16); }
      const float m1 = a1 * (1.f / 64.f), m2 = a2 * (1.f / 64.f);
      float o4[4];
#pragma unroll
      for (int e = 0; e < 4; ++e) o4[e] = (gx[e] - m1 - xh[e] * m2) * rstd;
      const unsigned lo = cvt_pk(o4[0], o4[1]);
      const unsigned hi = cvt_pk(o4[2], o4[3]);
      *(u32x2*)&sG2b[i * 72 + j4 * 4] = (u32x2){lo, hi};
      sG2c[(j4 * 4 + 0) * 24 + i] = (short)lo;
      sG2c[(j4 * 4 + 1) * 24 + i] = (short)(lo >> 16);
      sG2c[(j4 * 4 + 2) * 24 + i] = (short)hi;
      sG2c[(j4 * 4 + 3) * 24 + i] = (short)(hi >> 16);
    } else {
      const int pp = tid - 256;
      const float tok15 = sTok[15];
      unsigned uu[8];
#pragma unroll
      for (int jp = 0; jp < 8; ++jp) {
        const float v0 = bf2f(sX2b[(2 * jp) * 264 + pp]) * (tok15 * sLr[2 * jp]);
        const float v1 = bf2f(sX2b[(2 * jp + 1) * 264 + pp]) * (tok15 * sLr[2 * jp + 1]);
        uu[jp] = cvt_pk(v0, v1);
      }
      *(u32x4*)&la2T[pp * 24] = (u32x4){uu[0], uu[1], uu[2], uu[3]};
      *(u32x4*)&la2T[pp * 24 + 8] = (u32x4){uu[4], uu[5], uu[6], uu[7]};
    }
    __syncthreads();  // D

    // ---- E: gZ1 = (gZ2@W2^T)*gelu_bwd(Z1) -> sG1c | b2 update (tid<64)
    {
      short8 aG2[2];
      aG2[0] = *(const short8*)&sG2b[fr * 72 + hk];
      aG2[1] = *(const short8*)&sG2b[fr * 72 + 32 + hk];
#pragma unroll
      for (int t = 0; t < 2; ++t) {
        const int p = (nt0 + t) * 16 + fr;
        f32x4 g = zf4;
#pragma unroll
        for (int ks = 0; ks < 2; ++ks) {
          const int dg = ks * 32 + hk;          // d-group base; (d>>3) const across jj
          const int rb = w2row(dg) + (p ^ (((dg >> 3) & 3) << 3));
          short8 bw;
#pragma unroll
          for (int jj = 0; jj < 8; ++jj) bw[jj] = sW2dp[rb + jj * 264];
          g = MFMA16(aG2[ks], bw, g);
        }
        const unsigned lo = cvt_pk(g[0] * gelu_bwd_f(z1[t][0]), g[1] * gelu_bwd_f(z1[t][1]));
        const unsigned hi = cvt_pk(g[2] * gelu_bwd_f(z1[t][2]), g[3] * gelu_bwd_f(z1[t][3]));
        *(u32x2*)&sG1c[p * 24 + half * 4] = (u32x2){lo, hi};
      }
    }
    if (tid < 64) {
      float s = 0.f;
#pragma unroll
      for (int j = 0; j < 16; ++j) s += sLr[j] * bf2f(sG2c[tid * 24 + j]);
      sB2[tid] -= sTok[15] * s;
    }
    __syncthreads();  // E

    // ---- F: X2_bar | W1 reg-update | b1 update (tid<256)
    {
      short8 ac = zs8;
      if (half < 2) ac = *(const short8*)&sC1b[fr * 24 + hk];
#pragma unroll
      for (int t = 0; t < 2; ++t) {
        const int p = (nt0 + t) * 16 + fr;
        short8 bg = zs8;
        if (half < 2) bg = *(const short8*)&sG1c[p * 24 + hk];
        f32x4 corr = MFMA16(ac, bg, zf4);
#pragma unroll
        for (int qq = 0; qq < 4; ++qq)
          sXbb[(half * 4 + qq) * 264 + p] = f2bf(gelu_f(q1[t][qq] + b1p[t] - corr[qq]));
      }
    }
    {
#pragma unroll
      for (int r = 0; r < 8; ++r) {
        const int T = w * 8 + r, dt = T >> 4, pt = T & 15;
        short8 af = zs8, bg = zs8;
        if (half < 2) {
          af = *(const short8*)&la1T[(dt * 16 + fr) * 24 + hk];
          bg = *(const short8*)&sG1c[(pt * 16 + fr) * 24 + hk];
        }
        f32x4 dl = MFMA16(af, bg, zf4);
        const int pp = pt * 16 + fr, d0 = dt * 16 + half * 4;
        w1m[r][0] -= dl[0]; w1m[r][1] -= dl[1]; w1m[r][2] -= dl[2]; w1m[r][3] -= dl[3];
        const unsigned lo = cvt_pk(w1m[r][0], w1m[r][1]);
        const unsigned hi = cvt_pk(w1m[r][2], w1m[r][3]);
        *(u32x2*)&sW1b[pp * 72 + d0] = (u32x2){lo, hi};
      }
    }
    if (tid < 256) {
      float s = 0.f;
#pragma unroll
      for (int j = 0; j < 16; ++j) s += sLr[j] * bf2f(sG1c[tid * 24 + j]);
      sB1[tid] -= sTok[15] * s;
    }
    __syncthreads();  // F

    // ---- G: prefetch issue; Z2bar partial (w0-3) | C2 (w4)
    {
      const int nn = (n + 1 < NCHUNK) ? n + 1 : n;
      const long a1 = ((long)(b * LLL + nn * MBSZ + pf_i)) * WIDTH + h * 64 + pf_d;
      pk = *(const f32x2*)&Kb[a1];
      pq = *(const f32x2*)&Qb[a1];
      pv = *(const f32x2*)&Vb[a1];
      if (tid < 16) plr = LRb[(long)bh * 2048 + nn * MBSZ + tid];
    }
    f32x4 zbar = zf4;
    if (w < 4) {
      const int d = w * 16 + fr;
      const int sw = ((d >> 3) & 3) << 3;
      const int rb = w2row(d);
      f32x4 za = zf4, zb = zf4;
#pragma unroll
      for (int ks = 0; ks < 4; ++ks) {
        short8 a = *(const short8*)&sXbb[fr * 264 + ks * 32 + hk];
        short8 bfr = *(const short8*)&sW2dp[rb + ((ks * 32 + hk) ^ sw)];
        za = MFMA16(a, bfr, za);
      }
#pragma unroll
      for (int ks = 4; ks < 8; ++ks) {
        short8 a = *(const short8*)&sXbb[fr * 264 + ks * 32 + hk];
        short8 bfr = *(const short8*)&sW2dp[rb + ((ks * 32 + hk) ^ sw)];
        zb = MFMA16(a, bfr, zb);
      }
      zbar[0] = za[0] + zb[0]; zbar[1] = za[1] + zb[1];
      zbar[2] = za[2] + zb[2]; zbar[3] = za[3] + zb[3];
    } else if (w == 4) {
      f32x4 c = zf4;
#pragma unroll
      for (int ks = 0; ks < 8; ++ks) {
        short8 a = *(const short8*)&sXbb[fr * 264 + ks * 32 + hk];
        short8 bx = *(const short8*)&sX2b[fr * 264 + ks * 32 + hk];
        c = MFMA16(a, bx, c);
      }
#pragma unroll
      for (int qq = 0; qq < 4; ++qq) {
        const int i = half * 4 + qq, j = fr;
        sC2b[i * 24 + j] = f2bf((i >= j) ? sTok[i] * sLr[j] * (c[qq] + 1.0f) : 0.0f);
      }
    }
    __syncthreads();  // G

    // ---- H: Z2bar finalize (w0-3) + W2 reg-update (all waves)
    if (w < 4) {
      const int d = w * 16 + fr;
      short8 ac = zs8, bg = zs8;
      if (half < 2) {
        ac = *(const short8*)&sC2b[fr * 24 + hk];
        bg = *(const short8*)&sG2c[d * 24 + hk];
      }
      f32x4 corr = MFMA16(ac, bg, zf4);
#pragma unroll
      for (int qq = 0; qq < 4; ++qq)
        sZ2f[(half * 4 + qq) * 68 + d] = zbar[qq] + bb2old - corr[qq];
    }
    {
#pragma unroll
      for (int r = 0; r < 8; ++r) {
        const int T = w * 8 + r, pt = T & 15, dt = T >> 4;
        short8 af = zs8, bg = zs8;
        if (half < 2) {
          af = *(const short8*)&la2T[(pt * 16 + fr) * 24 + hk];
          bg = *(const short8*)&sG2c[(dt * 16 + fr) * 24 + hk];
        }
        f32x4 dl = MFMA16(af, bg, zf4);
        const int dd = dt * 16 + fr;
        const int swp = ((dd >> 3) & 3) << 3;
        const int p0 = pt * 16 + half * 4;
        w2m[r][0] -= dl[0]; w2m[r][1] -= dl[1]; w2m[r][2] -= dl[2]; w2m[r][3] -= dl[3];
        const unsigned lo = cvt_pk(w2m[r][0], w2m[r][1]);
        const unsigned hi = cvt_pk(w2m[r][2], w2m[r][3]);
        *(u32x2*)&sW2dp[w2row(dd) + (p0 ^ swp)] = (u32x2){lo, hi};
      }
    }
    __syncthreads();  // H

    // ---- I: XQW = XQ + ln_fwd(Z2_bar) -> Qb  (tid<256)
    if (tid < 256) {
      const int i = tid >> 4, j4 = tid & 15;
      const f32x4 z = *(const f32x4*)&sZ2f[i * 68 + j4 * 4];
      float s1 = z[0] + z[1] + z[2] + z[3];
      float s2 = z[0] * z[0] + z[1] * z[1] + z[2] * z[2] + z[3] * z[3];
#pragma unroll
      for (int o = 8; o; o >>= 1) { s1 += __shfl_xor(s1, o, 16); s2 += __shfl_xor(s2, o, 16); }
      const float mu = s1 * (1.f / 64.f);
      const float rstd = rsqrtf(s2 * (1.f / 64.f) - mu * mu + 1e-6f);
      const f32x4 g = *(const f32x4*)&sLnw[j4 * 4];
      const f32x4 bb = *(const f32x4*)&sLnb[j4 * 4];
      const f32x4 xq = *(const f32x4*)&sXQf[i * 68 + j4 * 4];
      f32x4 o4;
#pragma unroll
      for (int e = 0; e < 4; ++e) o4[e] = xq[e] + g[e] * ((z[e] - mu) * rstd) + bb[e];
      *(f32x4*)&Qb[gbase + (long)i * WIDTH + j4 * 4] = o4;
    }
    __syncthreads();  // I
  }
}

// ---------------- epilogue: tmp = gelu(G) * ln_fwd(XQW, post_w, post_b)
__global__ __launch_bounds__(256) void epi_kernel(const float* __restrict__ X,
                                                  const float* __restrict__ G,
                                                  const float* __restrict__ pw,
                                                  const float* __restrict__ pb,
                                                  float* __restrict__ T) {
  __shared__ float red[8];
  const int t = blockIdx.x, tid = threadIdx.x;
  const long base = (long)t * 1024 + tid * 4;
  f32x4 x = *(const f32x4*)&X[base];
  float s1 = x[0] + x[1] + x[2] + x[3];
  float s2 = x[0] * x[0] + x[1] * x[1] + x[2] * x[2] + x[3] * x[3];
#pragma unroll
  for (int o = 32; o; o >>= 1) { s1 += __shfl_xor(s1, o, 64); s2 += __shfl_xor(s2, o, 64); }
  const int wv = tid >> 6, ln = tid & 63;
  if (ln == 0) { red[wv] = s1; red[4 + wv] = s2; }
  __syncthreads();
  s1 = red[0] + red[1] + red[2] + red[3];
  s2 = red[4] + red[5] + red[6] + red[7];
  const float mu = s1 * (1.f / 1024.f);
  const float rstd = rsqrtf(s2 * (1.f / 1024.f) - mu * mu + 1e-6f);
  f32x4 g = *(const f32x4*)&G[base];
  f32x4 w = *(const f32x4*)&pw[tid * 4];
  f32x4 bb = *(const f32x4*)&pb[tid * 4];
  f32x4 o4;
#pragma unroll
  for (int e = 0; e < 4; ++e) {
    float y = w[e] * ((x[e] - mu) * rstd) + bb[e];
    o4[e] = gelu_f(g[e]) * y;
  }
  *(f32x4*)&T[base] = o4;
}

extern "C" void kernel_launch(void* const* d_in, const int* in_sizes, int n_in,
                              void* d_out, int out_size, void* d_ws, size_t ws_size,
                              hipStream_t stream) {
  const float* hs  = (const float*)d_in[0];
  const float* Wq  = (const float*)d_in[1];
  const float* Wk  = (const float*)d_in[2];
  const float* Wv  = (const float*)d_in[3];
  const float* Wo  = (const float*)d_in[4];
  const float* Wg  = (const float*)d_in[5];
  const float* lrw = (const float*)d_in[6];
  const float* lrb = (const float*)d_in[7];
  const float* lti = (const float*)d_in[8];
  const float* nw  = (const float*)d_in[9];
  const float* nb  = (const float*)d_in[10];
  const float* W1  = (const float*)d_in[11];
  const float* b1  = (const float*)d_in[12];
  const float* W2  = (const float*)d_in[13];
  const float* b2  = (const float*)d_in[14];
  const float* pw  = (const float*)d_in[15];
  const float* pb  = (const float*)d_in[16];
  float* out = (float*)d_out;
  float* ws = (float*)d_ws;

  float* Qb  = ws;
  float* Kb  = ws + 8388608;
  float* Vb  = ws + 16777216;
  float* Gb  = ws + 25165824;
  float* LRb = ws + 33554432;

  dim3 gg(128, 16);
  gemm_bt<<<gg, 256, 0, stream>>>(hs, Wq, Qb);
  gemm_bt<<<gg, 256, 0, stream>>>(hs, Wk, Kb);
  gemm_bt<<<gg, 256, 0, stream>>>(hs, Wv, Vb);
  gemm_bt<<<gg, 256, 0, stream>>>(hs, Wg, Gb);
  lr_kernel<<<8192, 256, 0, stream>>>(hs, lrw, lrb, LRb);
  scan_kernel<<<64, 512, 0, stream>>>(Qb, Kb, Vb, LRb, lti, nw, nb, W1, b1, W2, b2);
  epi_kernel<<<8192, 256, 0, stream>>>(Qb, Gb, pw, pb, Kb);
  gemm_bt<<<gg, 256, 0, stream>>>(Kb, Wo, out);
}

// Round 7
// 990.923 us; speedup vs baseline: 45.1870x; 1.0638x over previous
//
#include <hip/hip_runtime.h>

#define WIDTH 1024
#define MBSZ 16
#define LLL 2048
#define NCHUNK 128

typedef __attribute__((ext_vector_type(4))) float f32x4;
typedef __attribute__((ext_vector_type(2))) float f32x2;
typedef __attribute__((ext_vector_type(8))) short short8;
typedef __attribute__((ext_vector_type(4))) short short4v;
typedef __attribute__((ext_vector_type(2))) unsigned u32x2;
typedef __attribute__((ext_vector_type(4))) unsigned u32x4;

#define MFMA16(a, b, c) __builtin_amdgcn_mfma_f32_16x16x32_bf16((a), (b), (c), 0, 0, 0)

__device__ __forceinline__ short f2bf(float f) {
  unsigned u = __float_as_uint(f);
  u = (u + 0x7FFFu + ((u >> 16) & 1u)) >> 16;  // RNE f32->bf16
  return (short)u;
}
__device__ __forceinline__ float bf2f(short s) {
  return __uint_as_float(((unsigned)(unsigned short)s) << 16);
}
__device__ __forceinline__ unsigned cvt_pk(float lo, float hi) {
  unsigned r;
  asm("v_cvt_pk_bf16_f32 %0, %1, %2" : "=v"(r) : "v"(lo), "v"(hi));
  return r;
}
__device__ __forceinline__ float fast_e2u(float x) {
  return __builtin_amdgcn_exp2f(x * (2.30220776f + 0.10294322f * x * x));
}
__device__ __forceinline__ float gelu_f(float x) {
  float e = fast_e2u(x);
  return x * (1.0f - __builtin_amdgcn_rcpf(e + 1.0f));
}
__device__ __forceinline__ float gelu_bwd_f(float x) {
  float e = fast_e2u(x);
  float r = __builtin_amdgcn_rcpf(e + 1.0f);
  return 2.0f * x * r * (1.0f - r) * (0.79788456f + 0.1070322243f * x * x) + (1.0f - r);
}
__device__ __forceinline__ int w2row(int d) { return d * 264 + (d >> 3) * 24; }

// ---------------- one-shot fp32 -> bf16 conversion: hs(8M) + Wq,Wk,Wv,Wg,Wo (1M each)
__global__ __launch_bounds__(256) void cvt_kernel(const float* __restrict__ hs,
                                                  const float* __restrict__ Wq,
                                                  const float* __restrict__ Wk,
                                                  const float* __restrict__ Wv,
                                                  const float* __restrict__ Wg,
                                                  const float* __restrict__ Wo,
                                                  short* __restrict__ dst) {
  const long idx = ((long)blockIdx.x * 256 + threadIdx.x) * 8;
  if (idx >= 13631488L) return;
  const float* src;
  long off;
  if (idx < 8388608L)       { src = hs; off = idx; }
  else if (idx < 9437184L)  { src = Wq; off = idx - 8388608L; }
  else if (idx < 10485760L) { src = Wk; off = idx - 9437184L; }
  else if (idx < 11534336L) { src = Wv; off = idx - 10485760L; }
  else if (idx < 12582912L) { src = Wg; off = idx - 11534336L; }
  else                      { src = Wo; off = idx - 12582912L; }
  const f32x4 a = *(const f32x4*)(src + off);
  const f32x4 b = *(const f32x4*)(src + off + 4);
  u32x4 o;
  o[0] = cvt_pk(a[0], a[1]); o[1] = cvt_pk(a[2], a[3]);
  o[2] = cvt_pk(b[0], b[1]); o[3] = cvt_pk(b[2], b[3]);
  *(u32x4*)(dst + idx) = o;
}

// ---------------- C[8192][1024] = A[8192][1024] @ W[1024][1024]^T, bf16 inputs
// OUTBF=0: fp32 C; OUTBF=1: bf16 Cb
template <int OUTBF>
__global__ __launch_bounds__(256) void gemm_bt_b(const short* __restrict__ A,
                                                 const short* __restrict__ W,
                                                 float* __restrict__ C,
                                                 short* __restrict__ Cb) {
  __shared__ __align__(16) short sA[64][40];
  __shared__ __align__(16) short sB[64][40];
  const int tid = threadIdx.x;
  const int m0 = blockIdx.x * 64, n0 = blockIdx.y * 64;
  const int srow = tid >> 2, sk = (tid & 3) * 8;
  const int wv = tid >> 6, ln = tid & 63;
  const int fr = ln & 15, kh = (ln >> 4) * 8;
  f32x4 acc[4];
#pragma unroll
  for (int s = 0; s < 4; ++s) acc[s] = (f32x4){0.f, 0.f, 0.f, 0.f};
  const short* ga = A + (long)(m0 + srow) * 1024 + sk;
  const short* gw = W + (long)(n0 + srow) * 1024 + sk;
  for (int k0 = 0; k0 < 1024; k0 += 32) {
    const short8 a8 = *(const short8*)(ga + k0);
    const short8 w8 = *(const short8*)(gw + k0);
    *(short8*)&sA[srow][sk] = a8;
    *(short8*)&sB[srow][sk] = w8;
    __syncthreads();
    short8 af = *(const short8*)&sA[wv * 16 + fr][kh];
#pragma unroll
    for (int s = 0; s < 4; ++s) {
      short8 bf8 = *(const short8*)&sB[s * 16 + fr][kh];
      acc[s] = MFMA16(af, bf8, acc[s]);
    }
    __syncthreads();
  }
  const int orow = m0 + wv * 16 + (ln >> 4) * 4;
#pragma unroll
  for (int s = 0; s < 4; ++s)
#pragma unroll
    for (int q = 0; q < 4; ++q) {
      if (OUTBF)
        Cb[(long)(orow + q) * 1024 + n0 + s * 16 + fr] = f2bf(acc[s][q]);
      else
        C[(long)(orow + q) * 1024 + n0 + s * 16 + fr] = acc[s][q];
    }
}

// ---------------- lr_eta[b,h,t] = sigmoid(hs[t]·lr_w[h] + lr_b[h]) / 64
__global__ __launch_bounds__(256) void lr_kernel(const float* __restrict__ hs,
                                                 const float* __restrict__ lrw,
                                                 const float* __restrict__ lrb,
                                                 float* __restrict__ out) {
  __shared__ __align__(16) float row[1024];
  const int t = blockIdx.x, tid = threadIdx.x;
  *(f32x4*)&row[tid * 4] = *(const f32x4*)&hs[(long)t * 1024 + tid * 4];
  __syncthreads();
  const int hh = tid >> 4, j = tid & 15;
  const float* wrow = lrw + hh * 1024;
  float s = 0.f;
#pragma unroll 4
  for (int m = 0; m < 16; ++m) {
    const int c = j * 4 + m * 64;
    f32x4 x = *(const f32x4*)&row[c];
    f32x4 w = *(const f32x4*)&wrow[c];
    s += x[0] * w[0] + x[1] * w[1] + x[2] * w[2] + x[3] * w[3];
  }
#pragma unroll
  for (int o = 8; o; o >>= 1) s += __shfl_xor(s, o, 16);
  if (j == 0) {
    const float v = s + lrb[hh];
    const float sg = 1.f / (1.f + expf(-v));
    const int b = t >> 11, tr = t & 2047;
    out[((b << 4) + hh) * 2048 + tr] = sg * (1.f / 64.f);
  }
}

// ---------------- sequential TTT scan: one block of 512 per (b,h)  (unchanged from R6)
__global__ __launch_bounds__(512, 2) void scan_kernel(
    float* __restrict__ Qb, const float* __restrict__ Kb, const float* __restrict__ Vb,
    const float* __restrict__ LRb, const float* __restrict__ lti,
    const float* __restrict__ nw, const float* __restrict__ nb,
    const float* __restrict__ W1in, const float* __restrict__ b1in,
    const float* __restrict__ W2in, const float* __restrict__ b2in) {
  __shared__ __align__(16) short sW1b[256 * 72];
  __shared__ __align__(16) short sW2dp[64 * 264 + 192];
  __shared__ __align__(16) short la1T[64 * 24];
  __shared__ __align__(16) short la2T[256 * 24];
  __shared__ __align__(16) short sX1b[16 * 72];
  __shared__ __align__(16) short sXQb[16 * 72];
  __shared__ __align__(16) float sXQf[16 * 68];
  __shared__ __align__(16) float sTg[16 * 72];
  __shared__ __align__(16) short sX2b[16 * 264];
  __shared__ __align__(16) short sXbb[16 * 264];
  __shared__ __align__(16) short sG1c[256 * 24];
  __shared__ __align__(16) short sG2b[16 * 72];
  __shared__ __align__(16) short sG2c[64 * 24];
  __shared__ __align__(16) float sZ2f[16 * 68];
  __shared__ __align__(16) short sC1b[16 * 24];
  __shared__ __align__(16) short sC2b[16 * 24];
  __shared__ __align__(16) float sB1[256];
  __shared__ __align__(16) float sB2[64];
  __shared__ float sLr[16];
  __shared__ float sTok[16];
  __shared__ __align__(16) float sLnw[64];
  __shared__ __align__(16) float sLnb[64];

  const int bh = blockIdx.x, b = bh >> 4, h = bh & 15;
  const int tid = threadIdx.x;
  const int w = tid >> 6, ln = tid & 63;
  const int fr = ln & 15, half = ln >> 4, hk = half * 8;
  const int nt0 = 2 * w;

  float w1m[8][4], w2m[8][4];
#pragma unroll
  for (int r = 0; r < 8; ++r) {
    const int T = w * 8 + r, dt = T >> 4, pt = T & 15;
#pragma unroll
    for (int qq = 0; qq < 4; ++qq) {
      w1m[r][qq] = W1in[h * 16384 + (dt * 16 + half * 4 + qq) * 256 + pt * 16 + fr];
      w2m[r][qq] = W2in[h * 16384 + (pt * 16 + half * 4 + qq) * 64 + dt * 16 + fr];
    }
  }
  for (int e = tid; e < 16384; e += 512) {
    {
      const int d = e >> 8, p = e & 255;
      sW1b[p * 72 + d] = f2bf(W1in[h * 16384 + e]);
    }
    {
      const int p = e >> 6, d = e & 63;
      sW2dp[w2row(d) + (p ^ (((d >> 3) & 3) << 3))] = f2bf(W2in[h * 16384 + e]);
    }
  }
  if (tid < 256) sB1[tid] = b1in[h * 256 + tid];
  if (tid < 64) { sB2[tid] = b2in[h * 64 + tid]; sLnw[tid] = nw[h * 64 + tid]; sLnb[tid] = nb[h * 64 + tid]; }
  if (tid < 16) sTok[tid] = fmaxf(1.0f / (float)(tid + 1) + lti[tid], 0.0f);

  const f32x4 zf4 = (f32x4){0.f, 0.f, 0.f, 0.f};
  short8 zs8;
#pragma unroll
  for (int j = 0; j < 8; ++j) zs8[j] = 0;

  const int pf_i = tid >> 5;
  const int pf_d = (tid & 31) * 2;
  f32x2 pk, pq, pv;
  float plr = 0.f;
  {
    const long a0 = ((long)(b * LLL + pf_i)) * WIDTH + h * 64 + pf_d;
    pk = *(const f32x2*)&Kb[a0];
    pq = *(const f32x2*)&Qb[a0];
    pv = *(const f32x2*)&Vb[a0];
    if (tid < 16) plr = LRb[(long)bh * 2048 + tid];
  }

  for (int n = 0; n < NCHUNK; ++n) {
    const long gbase = ((long)(b * LLL + n * MBSZ)) * WIDTH + h * 64;

    {
      *(unsigned*)&sX1b[pf_i * 72 + pf_d] = cvt_pk(pk[0], pk[1]);
      *(unsigned*)&sXQb[pf_i * 72 + pf_d] = cvt_pk(pq[0], pq[1]);
      sXQf[pf_i * 68 + pf_d] = pq[0];
      sXQf[pf_i * 68 + pf_d + 1] = pq[1];
      sTg[pf_i * 72 + pf_d] = pv[0] - pk[0];
      sTg[pf_i * 72 + pf_d + 1] = pv[1] - pk[1];
      if (tid < 16) sLr[tid] = plr;
    }
    __syncthreads();  // A

    short8 aX1[2], aXQ[2];
    aX1[0] = *(const short8*)&sX1b[fr * 72 + hk];
    aX1[1] = *(const short8*)&sX1b[fr * 72 + 32 + hk];
    aXQ[0] = *(const short8*)&sXQb[fr * 72 + hk];
    aXQ[1] = *(const short8*)&sXQb[fr * 72 + 32 + hk];
    f32x4 z1[2], q1[2];
    float b1p[2];
#pragma unroll
    for (int t = 0; t < 2; ++t) {
      const int p = (nt0 + t) * 16 + fr;
      z1[t] = zf4; q1[t] = zf4;
#pragma unroll
      for (int ks = 0; ks < 2; ++ks) {
        short8 bw = *(const short8*)&sW1b[p * 72 + ks * 32 + hk];
        z1[t] = MFMA16(aX1[ks], bw, z1[t]);
        q1[t] = MFMA16(aXQ[ks], bw, q1[t]);
      }
      b1p[t] = sB1[p];
#pragma unroll
      for (int qq = 0; qq < 4; ++qq) {
        z1[t][qq] += b1p[t];
        sX2b[(half * 4 + qq) * 264 + p] = f2bf(gelu_f(z1[t][qq]));
      }
    }
    {
      const float tok15 = sTok[15];
      const int d = tid >> 3, j0 = (tid & 7) * 2;
      const float v0 = bf2f(sX1b[j0 * 72 + d]) * (tok15 * sLr[j0]);
      const float v1 = bf2f(sX1b[(j0 + 1) * 72 + d]) * (tok15 * sLr[j0 + 1]);
      *(unsigned*)&la1T[d * 24 + j0] = cvt_pk(v0, v1);
    }
    if (w == 0) {
      f32x4 c = MFMA16(aXQ[0], aX1[0], zf4);
      c = MFMA16(aXQ[1], aX1[1], c);
#pragma unroll
      for (int qq = 0; qq < 4; ++qq) {
        const int i = half * 4 + qq, j = fr;
        sC1b[i * 24 + j] = f2bf((i >= j) ? sTok[i] * sLr[j] * (c[qq] + 1.0f) : 0.0f);
      }
    }
    __syncthreads();  // B

    float bb2old = 0.f;
    if (w < 4) {
      const int d = w * 16 + fr;
      const int sw = ((d >> 3) & 3) << 3;
      const int rb = w2row(d);
      f32x4 za = zf4, zb = zf4;
#pragma unroll
      for (int ks = 0; ks < 4; ++ks) {
        short8 a = *(const short8*)&sX2b[fr * 264 + ks * 32 + hk];
        short8 bfr = *(const short8*)&sW2dp[rb + ((ks * 32 + hk) ^ sw)];
        za = MFMA16(a, bfr, za);
      }
#pragma unroll
      for (int ks = 4; ks < 8; ++ks) {
        short8 a = *(const short8*)&sX2b[fr * 264 + ks * 32 + hk];
        short8 bfr = *(const short8*)&sW2dp[rb + ((ks * 32 + hk) ^ sw)];
        zb = MFMA16(a, bfr, zb);
      }
      bb2old = sB2[d];
#pragma unroll
      for (int qq = 0; qq < 4; ++qq)
        sZ2f[(half * 4 + qq) * 68 + d] = za[qq] + zb[qq] + bb2old;
    }
    __syncthreads();  // C

    if (tid < 256) {
      const int i = tid >> 4, j4 = tid & 15;
      const f32x4 z = *(const f32x4*)&sZ2f[i * 68 + j4 * 4];
      float s1 = z[0] + z[1] + z[2] + z[3];
      float s2 = z[0] * z[0] + z[1] * z[1] + z[2] * z[2] + z[3] * z[3];
#pragma unroll
      for (int o = 8; o; o >>= 1) { s1 += __shfl_xor(s1, o, 16); s2 += __shfl_xor(s2, o, 16); }
      const float mu = s1 * (1.f / 64.f);
      const float rstd = rsqrtf(s2 * (1.f / 64.f) - mu * mu + 1e-6f);
      const f32x4 g = *(const f32x4*)&sLnw[j4 * 4];
      const f32x4 bb = *(const f32x4*)&sLnb[j4 * 4];
      const f32x4 tg = *(const f32x4*)&sTg[i * 72 + j4 * 4];
      f32x4 xh, gx;
      float a1 = 0.f, a2 = 0.f;
#pragma unroll
      for (int e = 0; e < 4; ++e) {
        xh[e] = (z[e] - mu) * rstd;
        gx[e] = (g[e] * xh[e] + bb[e] - tg[e]) * g[e];
        a1 += gx[e]; a2 += gx[e] * xh[e];
      }
#pragma unroll
      for (int o = 8; o; o >>= 1) { a1 += __shfl_xor(a1, o, 16); a2 += __shfl_xor(a2, o, 16); }
      const float m1 = a1 * (1.f / 64.f), m2 = a2 * (1.f / 64.f);
      float o4[4];
#pragma unroll
      for (int e = 0; e < 4; ++e) o4[e] = (gx[e] - m1 - xh[e] * m2) * rstd;
      const unsigned lo = cvt_pk(o4[0], o4[1]);
      const unsigned hi = cvt_pk(o4[2], o4[3]);
      *(u32x2*)&sG2b[i * 72 + j4 * 4] = (u32x2){lo, hi};
      sG2c[(j4 * 4 + 0) * 24 + i] = (short)lo;
      sG2c[(j4 * 4 + 1) * 24 + i] = (short)(lo >> 16);
      sG2c[(j4 * 4 + 2) * 24 + i] = (short)hi;
      sG2c[(j4 * 4 + 3) * 24 + i] = (short)(hi >> 16);
    } else {
      const int pp = tid - 256;
      const float tok15 = sTok[15];
      unsigned uu[8];
#pragma unroll
      for (int jp = 0; jp < 8; ++jp) {
        const float v0 = bf2f(sX2b[(2 * jp) * 264 + pp]) * (tok15 * sLr[2 * jp]);
        const float v1 = bf2f(sX2b[(2 * jp + 1) * 264 + pp]) * (tok15 * sLr[2 * jp + 1]);
        uu[jp] = cvt_pk(v0, v1);
      }
      *(u32x4*)&la2T[pp * 24] = (u32x4){uu[0], uu[1], uu[2], uu[3]};
      *(u32x4*)&la2T[pp * 24 + 8] = (u32x4){uu[4], uu[5], uu[6], uu[7]};
    }
    __syncthreads();  // D

    {
      short8 aG2[2];
      aG2[0] = *(const short8*)&sG2b[fr * 72 + hk];
      aG2[1] = *(const short8*)&sG2b[fr * 72 + 32 + hk];
#pragma unroll
      for (int t = 0; t < 2; ++t) {
        const int p = (nt0 + t) * 16 + fr;
        f32x4 g = zf4;
#pragma unroll
        for (int ks = 0; ks < 2; ++ks) {
          const int dg = ks * 32 + hk;
          const int rb = w2row(dg) + (p ^ (((dg >> 3) & 3) << 3));
          short8 bw;
#pragma unroll
          for (int jj = 0; jj < 8; ++jj) bw[jj] = sW2dp[rb + jj * 264];
          g = MFMA16(aG2[ks], bw, g);
        }
        const unsigned lo = cvt_pk(g[0] * gelu_bwd_f(z1[t][0]), g[1] * gelu_bwd_f(z1[t][1]));
        const unsigned hi = cvt_pk(g[2] * gelu_bwd_f(z1[t][2]), g[3] * gelu_bwd_f(z1[t][3]));
        *(u32x2*)&sG1c[p * 24 + half * 4] = (u32x2){lo, hi};
      }
    }
    if (tid < 64) {
      float s = 0.f;
#pragma unroll
      for (int j = 0; j < 16; ++j) s += sLr[j] * bf2f(sG2c[tid * 24 + j]);
      sB2[tid] -= sTok[15] * s;
    }
    __syncthreads();  // E

    {
      short8 ac = zs8;
      if (half < 2) ac = *(const short8*)&sC1b[fr * 24 + hk];
#pragma unroll
      for (int t = 0; t < 2; ++t) {
        const int p = (nt0 + t) * 16 + fr;
        short8 bg = zs8;
        if (half < 2) bg = *(const short8*)&sG1c[p * 24 + hk];
        f32x4 corr = MFMA16(ac, bg, zf4);
#pragma unroll
        for (int qq = 0; qq < 4; ++qq)
          sXbb[(half * 4 + qq) * 264 + p] = f2bf(gelu_f(q1[t][qq] + b1p[t] - corr[qq]));
      }
    }
    {
#pragma unroll
      for (int r = 0; r < 8; ++r) {
        const int T = w * 8 + r, dt = T >> 4, pt = T & 15;
        short8 af = zs8, bg = zs8;
        if (half < 2) {
          af = *(const short8*)&la1T[(dt * 16 + fr) * 24 + hk];
          bg = *(const short8*)&sG1c[(pt * 16 + fr) * 24 + hk];
        }
        f32x4 dl = MFMA16(af, bg, zf4);
        const int pp = pt * 16 + fr, d0 = dt * 16 + half * 4;
        w1m[r][0] -= dl[0]; w1m[r][1] -= dl[1]; w1m[r][2] -= dl[2]; w1m[r][3] -= dl[3];
        const unsigned lo = cvt_pk(w1m[r][0], w1m[r][1]);
        const unsigned hi = cvt_pk(w1m[r][2], w1m[r][3]);
        *(u32x2*)&sW1b[pp * 72 + d0] = (u32x2){lo, hi};
      }
    }
    if (tid < 256) {
      float s = 0.f;
#pragma unroll
      for (int j = 0; j < 16; ++j) s += sLr[j] * bf2f(sG1c[tid * 24 + j]);
      sB1[tid] -= sTok[15] * s;
    }
    __syncthreads();  // F

    {
      const int nn = (n + 1 < NCHUNK) ? n + 1 : n;
      const long a1 = ((long)(b * LLL + nn * MBSZ + pf_i)) * WIDTH + h * 64 + pf_d;
      pk = *(const f32x2*)&Kb[a1];
      pq = *(const f32x2*)&Qb[a1];
      pv = *(const f32x2*)&Vb[a1];
      if (tid < 16) plr = LRb[(long)bh * 2048 + nn * MBSZ + tid];
    }
    f32x4 zbar = zf4;
    if (w < 4) {
      const int d = w * 16 + fr;
      const int sw = ((d >> 3) & 3) << 3;
      const int rb = w2row(d);
      f32x4 za = zf4, zb = zf4;
#pragma unroll
      for (int ks = 0; ks < 4; ++ks) {
        short8 a = *(const short8*)&sXbb[fr * 264 + ks * 32 + hk];
        short8 bfr = *(const short8*)&sW2dp[rb + ((ks * 32 + hk) ^ sw)];
        za = MFMA16(a, bfr, za);
      }
#pragma unroll
      for (int ks = 4; ks < 8; ++ks) {
        short8 a = *(const short8*)&sXbb[fr * 264 + ks * 32 + hk];
        short8 bfr = *(const short8*)&sW2dp[rb + ((ks * 32 + hk) ^ sw)];
        zb = MFMA16(a, bfr, zb);
      }
      zbar[0] = za[0] + zb[0]; zbar[1] = za[1] + zb[1];
      zbar[2] = za[2] + zb[2]; zbar[3] = za[3] + zb[3];
    } else if (w == 4) {
      f32x4 c = zf4;
#pragma unroll
      for (int ks = 0; ks < 8; ++ks) {
        short8 a = *(const short8*)&sXbb[fr * 264 + ks * 32 + hk];
        short8 bx = *(const short8*)&sX2b[fr * 264 + ks * 32 + hk];
        c = MFMA16(a, bx, c);
      }
#pragma unroll
      for (int qq = 0; qq < 4; ++qq) {
        const int i = half * 4 + qq, j = fr;
        sC2b[i * 24 + j] = f2bf((i >= j) ? sTok[i] * sLr[j] * (c[qq] + 1.0f) : 0.0f);
      }
    }
    __syncthreads();  // G

    if (w < 4) {
      const int d = w * 16 + fr;
      short8 ac = zs8, bg = zs8;
      if (half < 2) {
        ac = *(const short8*)&sC2b[fr * 24 + hk];
        bg = *(const short8*)&sG2c[d * 24 + hk];
      }
      f32x4 corr = MFMA16(ac, bg, zf4);
#pragma unroll
      for (int qq = 0; qq < 4; ++qq)
        sZ2f[(half * 4 + qq) * 68 + d] = zbar[qq] + bb2old - corr[qq];
    }
    {
#pragma unroll
      for (int r = 0; r < 8; ++r) {
        const int T = w * 8 + r, pt = T & 15, dt = T >> 4;
        short8 af = zs8, bg = zs8;
        if (half < 2) {
          af = *(const short8*)&la2T[(pt * 16 + fr) * 24 + hk];
          bg = *(const short8*)&sG2c[(dt * 16 + fr) * 24 + hk];
        }
        f32x4 dl = MFMA16(af, bg, zf4);
        const int dd = dt * 16 + fr;
        const int swp = ((dd >> 3) & 3) << 3;
        const int p0 = pt * 16 + half * 4;
        w2m[r][0] -= dl[0]; w2m[r][1] -= dl[1]; w2m[r][2] -= dl[2]; w2m[r][3] -= dl[3];
        const unsigned lo = cvt_pk(w2m[r][0], w2m[r][1]);
        const unsigned hi = cvt_pk(w2m[r][2], w2m[r][3]);
        *(u32x2*)&sW2dp[w2row(dd) + (p0 ^ swp)] = (u32x2){lo, hi};
      }
    }
    __syncthreads();  // H

    if (tid < 256) {
      const int i = tid >> 4, j4 = tid & 15;
      const f32x4 z = *(const f32x4*)&sZ2f[i * 68 + j4 * 4];
      float s1 = z[0] + z[1] + z[2] + z[3];
      float s2 = z[0] * z[0] + z[1] * z[1] + z[2] * z[2] + z[3] * z[3];
#pragma unroll
      for (int o = 8; o; o >>= 1) { s1 += __shfl_xor(s1, o, 16); s2 += __shfl_xor(s2, o, 16); }
      const float mu = s1 * (1.f / 64.f);
      const float rstd = rsqrtf(s2 * (1.f / 64.f) - mu * mu + 1e-6f);
      const f32x4 g = *(const f32x4*)&sLnw[j4 * 4];
      const f32x4 bb = *(const f32x4*)&sLnb[j4 * 4];
      const f32x4 xq = *(const f32x4*)&sXQf[i * 68 + j4 * 4];
      f32x4 o4;
#pragma unroll
      for (int e = 0; e < 4; ++e) o4[e] = xq[e] + g[e] * ((z[e] - mu) * rstd) + bb[e];
      *(f32x4*)&Qb[gbase + (long)i * WIDTH + j4 * 4] = o4;
    }
    __syncthreads();  // I
  }
}

// ---------------- epilogue: T(bf16) = gelu(G_bf16) * ln_fwd(XQW_f32, post_w, post_b)
__global__ __launch_bounds__(256) void epi_kernel(const float* __restrict__ X,
                                                  const short* __restrict__ G,
                                                  const float* __restrict__ pw,
                                                  const float* __restrict__ pb,
                                                  short* __restrict__ T) {
  __shared__ float red[8];
  const int t = blockIdx.x, tid = threadIdx.x;
  const long base = (long)t * 1024 + tid * 4;
  f32x4 x = *(const f32x4*)&X[base];
  float s1 = x[0] + x[1] + x[2] + x[3];
  float s2 = x[0] * x[0] + x[1] * x[1] + x[2] * x[2] + x[3] * x[3];
#pragma unroll
  for (int o = 32; o; o >>= 1) { s1 += __shfl_xor(s1, o, 64); s2 += __shfl_xor(s2, o, 64); }
  const int wv = tid >> 6, ln = tid & 63;
  if (ln == 0) { red[wv] = s1; red[4 + wv] = s2; }
  __syncthreads();
  s1 = red[0] + red[1] + red[2] + red[3];
  s2 = red[4] + red[5] + red[6] + red[7];
  const float mu = s1 * (1.f / 1024.f);
  const float rstd = rsqrtf(s2 * (1.f / 1024.f) - mu * mu + 1e-6f);
  const short4v g4 = *(const short4v*)&G[base];
  f32x4 w = *(const f32x4*)&pw[tid * 4];
  f32x4 bb = *(const f32x4*)&pb[tid * 4];
  float o4[4];
#pragma unroll
  for (int e = 0; e < 4; ++e) {
    float y = w[e] * ((x[e] - mu) * rstd) + bb[e];
    o4[e] = gelu_f(bf2f(g4[e])) * y;
  }
  *(u32x2*)&T[base] = (u32x2){cvt_pk(o4[0], o4[1]), cvt_pk(o4[2], o4[3])};
}

extern "C" void kernel_launch(void* const* d_in, const int* in_sizes, int n_in,
                              void* d_out, int out_size, void* d_ws, size_t ws_size,
                              hipStream_t stream) {
  const float* hs  = (const float*)d_in[0];
  const float* Wq  = (const float*)d_in[1];
  const float* Wk  = (const float*)d_in[2];
  const float* Wv  = (const float*)d_in[3];
  const float* Wo  = (const float*)d_in[4];
  const float* Wg  = (const float*)d_in[5];
  const float* lrw = (const float*)d_in[6];
  const float* lrb = (const float*)d_in[7];
  const float* lti = (const float*)d_in[8];
  const float* nw  = (const float*)d_in[9];
  const float* nb  = (const float*)d_in[10];
  const float* W1  = (const float*)d_in[11];
  const float* b1  = (const float*)d_in[12];
  const float* W2  = (const float*)d_in[13];
  const float* b2  = (const float*)d_in[14];
  const float* pw  = (const float*)d_in[15];
  const float* pb  = (const float*)d_in[16];
  float* out = (float*)d_out;
  float* ws = (float*)d_ws;

  float* Qb  = ws;                    // 8M f32
  float* Kb  = ws + 8388608;          // 8M f32 (T bf16 overlays after scan)
  float* Vb  = ws + 16777216;         // 8M f32 (gate bf16 overlays after scan)
  float* LRb = ws + 25165824;         // 131072 f32
  short* hsb = (short*)(ws + 25296896);  // 8M bf16
  short* Wqb = hsb + 8388608;         // 1M bf16 each
  short* Wkb = Wqb + 1048576;
  short* Wvb = Wkb + 1048576;
  short* Wgb = Wvb + 1048576;
  short* Wob = Wgb + 1048576;
  short* Tb  = (short*)Kb;
  short* Gbb = (short*)Vb;

  dim3 gg(128, 16);
  cvt_kernel<<<6656, 256, 0, stream>>>(hs, Wq, Wk, Wv, Wg, Wo, hsb);
  gemm_bt_b<0><<<gg, 256, 0, stream>>>(hsb, Wqb, Qb, nullptr);
  gemm_bt_b<0><<<gg, 256, 0, stream>>>(hsb, Wkb, Kb, nullptr);
  gemm_bt_b<0><<<gg, 256, 0, stream>>>(hsb, Wvb, Vb, nullptr);
  lr_kernel<<<8192, 256, 0, stream>>>(hs, lrw, lrb, LRb);
  scan_kernel<<<64, 512, 0, stream>>>(Qb, Kb, Vb, LRb, lti, nw, nb, W1, b1, W2, b2);
  gemm_bt_b<1><<<gg, 256, 0, stream>>>(hsb, Wgb, nullptr, Gbb);   // gate after scan: Vb dead
  epi_kernel<<<8192, 256, 0, stream>>>(Qb, Gbb, pw, pb, Tb);      // Kb dead
  gemm_bt_b<0><<<gg, 256, 0, stream>>>(Tb, Wob, out, nullptr);
}